// Round 8
// baseline (1116.401 us; speedup 1.0000x reference)
//
#include <hip/hip_runtime.h>
#include <stdint.h>

#define N_NODES 100000
#define N_EDGES 3200000
#define IN_DIM  512
#define HID     256
#define NCLS    16

// graph-prep geometry
#define DBLK   256                   // blocks (one per CU)
#define DCHUNK (N_EDGES / DBLK)      // 12500 edges per block
#define NBKT   98                    // dst buckets of 1024 nodes  ((N_NODES+1023)>>10)
#define NTILE  ((N_NODES + 255) / 256)   // 391 scan tiles

typedef unsigned short u16;
typedef __attribute__((ext_vector_type(8))) short short8;
typedef __attribute__((ext_vector_type(4))) float float4v;

// ---------------- bf16 helpers ----------------
__device__ __forceinline__ float bf2f(u16 u) {
  return __uint_as_float(((uint32_t)u) << 16);
}
__device__ __forceinline__ u16 f2bf(float f) {   // round-to-nearest-even
  uint32_t u = __float_as_uint(f);
  return (u16)((u + 0x7fffu + ((u >> 16) & 1u)) >> 16);
}
__device__ __forceinline__ void acc8(float* a, uint4 v) {
  a[0] += bf2f((u16)(v.x & 0xffffu)); a[1] += bf2f((u16)(v.x >> 16));
  a[2] += bf2f((u16)(v.y & 0xffffu)); a[3] += bf2f((u16)(v.y >> 16));
  a[4] += bf2f((u16)(v.z & 0xffffu)); a[5] += bf2f((u16)(v.z >> 16));
  a[6] += bf2f((u16)(v.w & 0xffffu)); a[7] += bf2f((u16)(v.w >> 16));
}

// async global->LDS, 16B per lane: LDS dest = wave-uniform base + lane*16
__device__ __forceinline__ void gload16(const void* g, void* l) {
  __builtin_amdgcn_global_load_lds(
      (const __attribute__((address_space(1))) uint32_t*)g,
      (__attribute__((address_space(3))) uint32_t*)l, 16, 0, 0);
}

// ---------------- Threefry-2x32 (exact JAX schedule, partitionable mode) ----------------
__host__ __device__ __forceinline__ uint32_t rotl32(uint32_t v, int d) {
  return (v << d) | (v >> (32 - d));
}

__host__ __device__ __forceinline__ void threefry2x32(uint32_t k0, uint32_t k1,
    uint32_t x0, uint32_t x1, uint32_t& o0, uint32_t& o1) {
  uint32_t ks0 = k0, ks1 = k1, ks2 = k0 ^ k1 ^ 0x1BD11BDAu;
  x0 += ks0; x1 += ks1;
#define TF_R(r) { x0 += x1; x1 = rotl32(x1, r); x1 ^= x0; }
  TF_R(13) TF_R(15) TF_R(26) TF_R(6)
  x0 += ks1; x1 += ks2 + 1u;
  TF_R(17) TF_R(29) TF_R(16) TF_R(24)
  x0 += ks2; x1 += ks0 + 2u;
  TF_R(13) TF_R(15) TF_R(26) TF_R(6)
  x0 += ks0; x1 += ks1 + 3u;
  TF_R(17) TF_R(29) TF_R(16) TF_R(24)
  x0 += ks1; x1 += ks2 + 4u;
  TF_R(13) TF_R(15) TF_R(26) TF_R(6)
  x0 += ks2; x1 += ks0 + 5u;
#undef TF_R
  o0 = x0; o1 = x1;
}

__host__ __device__ __forceinline__ uint32_t tf_bits32(uint32_t k0, uint32_t k1, uint32_t idx) {
  uint32_t o0, o1;
  threefry2x32(k0, k1, 0u, idx, o0, o1);
  return o0 ^ o1;
}

// ---------------- erfinv: XLA/Giles f32 polynomial ----------------
__device__ __forceinline__ float erfinv_f32(float x) {
  float w = -log1pf(-x * x);
  float p;
  if (w < 5.0f) {
    w -= 2.5f;
    p = 2.81022636e-08f;
    p = fmaf(p, w, 3.43273939e-07f);
    p = fmaf(p, w, -3.5233877e-06f);
    p = fmaf(p, w, -4.39150654e-06f);
    p = fmaf(p, w, 0.00021858087f);
    p = fmaf(p, w, -0.00125372503f);
    p = fmaf(p, w, -0.00417768164f);
    p = fmaf(p, w, 0.246640727f);
    p = fmaf(p, w, 1.50140941f);
  } else {
    w = sqrtf(w) - 3.0f;
    p = -0.000200214257f;
    p = fmaf(p, w, 0.000100950558f);
    p = fmaf(p, w, 0.00134934322f);
    p = fmaf(p, w, -0.00367342844f);
    p = fmaf(p, w, 0.00573950773f);
    p = fmaf(p, w, -0.0076224613f);
    p = fmaf(p, w, 0.00943887047f);
    p = fmaf(p, w, 1.00167406f);
    p = fmaf(p, w, 2.83297682f);
  }
  return p * x;
}

// ---------------- prep1: degrees (global atomics) + bucket partition, one kernel ----------------
// deg[0..N): out-degree, deg[N..2N): in-degree. Both arrays 400 KB -> L2-resident atomics.
// Pass 1: count degrees + per-block bucket counts. Pass 2 (L2-warm re-read): bucket-sort
// this block's chunk into its private ebuf region (100 KB, L2-resident writes).
__global__ __launch_bounds__(1024) void prep1_k(
    const int* __restrict__ esrc, const int* __restrict__ edst,
    uint32_t* __restrict__ deg, uint32_t* __restrict__ bofs_g,
    unsigned long long* __restrict__ ebuf) {
  __shared__ uint32_t bcnt[NBKT + 1];
  const int b = blockIdx.x, tid = threadIdx.x;
  if (tid < NBKT + 1) bcnt[tid] = 0u;
  __syncthreads();
  const int ebase = b * DCHUNK;
  for (int e = ebase + tid; e < ebase + DCHUNK; e += 1024) {
    int s = esrc[e], d = edst[e];
    atomicAdd(&deg[s], 1u);
    atomicAdd(&deg[N_NODES + d], 1u);
    atomicAdd(&bcnt[d >> 10], 1u);
  }
  __syncthreads();
  if (tid == 0) {   // exclusive scan of 98 bucket counts
    uint32_t run = 0;
    for (int k = 0; k < NBKT; ++k) { uint32_t c = bcnt[k]; bcnt[k] = run; run += c; }
    bcnt[NBKT] = run;   // == DCHUNK
  }
  __syncthreads();
  if (tid < NBKT + 1) bofs_g[b * (NBKT + 1) + tid] = bcnt[tid];
  __syncthreads();
  for (int e = ebase + tid; e < ebase + DCHUNK; e += 1024) {
    int d = edst[e], s = esrc[e];
    uint32_t slot = atomicAdd(&bcnt[d >> 10], 1u);
    ebuf[(size_t)b * DCHUNK + slot] = ((unsigned long long)(uint32_t)s << 32) | (uint32_t)d;
  }
}

// ---------------- scan1: inv-sqrts + intra-tile exclusive scan of in-degree ----------------
__global__ void scan1_k(const uint32_t* __restrict__ deg, float* __restrict__ out_is,
                        float* __restrict__ in_is, int* __restrict__ row_ofs,
                        int* __restrict__ tile_sum) {
  const int tid = threadIdx.x;
  const int n = blockIdx.x * 256 + tid;
  const int lane = tid & 63, wv = tid >> 6;
  uint32_t ti = 0;
  if (n < N_NODES) {
    uint32_t to = deg[n];
    ti = deg[N_NODES + n];
    out_is[n] = rsqrtf(fmaxf((float)to, 1.0f));
    in_is[n]  = rsqrtf(fmaxf((float)ti, 1.0f));
  }
  int sc = (int)ti;
#pragma unroll
  for (int d = 1; d < 64; d <<= 1) {
    int t = __shfl_up(sc, d, 64);
    if (lane >= d) sc += t;
  }
  __shared__ int ws[4];
  if (lane == 63) ws[wv] = sc;
  __syncthreads();
  int wbase = 0;
#pragma unroll
  for (int i = 0; i < 4; ++i) if (i < wv) wbase += ws[i];
  if (n < N_NODES) row_ofs[n] = wbase + sc - (int)ti;   // tile-local exclusive prefix
  if (tid == 0) tile_sum[blockIdx.x] = ws[0] + ws[1] + ws[2] + ws[3];
}

// ---------------- fixup: add tile bases (parallel over tiles) ----------------
__global__ void fixup_k(const int* __restrict__ tile_sum, int* __restrict__ row_ofs) {
  const int b = blockIdx.x, tid = threadIdx.x;
  const int lane = tid & 63, wv = tid >> 6;
  int v = 0;
  if (tid < b) v = tile_sum[tid];
  if (tid + 256 < b) v += tile_sum[tid + 256];
#pragma unroll
  for (int m = 1; m < 64; m <<= 1) v += __shfl_xor(v, m, 64);
  __shared__ int wr[4];
  if (lane == 0) wr[wv] = v;
  __syncthreads();
  const int base = wr[0] + wr[1] + wr[2] + wr[3];
  const int n = b * 256 + tid;
  if (n < N_NODES) row_ofs[n] += base;
  if (b == (int)gridDim.x - 1 && tid == 0) row_ofs[N_NODES] = base + tile_sum[b];
}

// ---------------- bplace: per-bucket scatter to final CSR slots (L2-local) ----------------
__global__ __launch_bounds__(1024) void bplace_k(
    const unsigned long long* __restrict__ ebuf, const uint32_t* __restrict__ bofs_g,
    const int* __restrict__ row_ofs, int* __restrict__ csr) {
  __shared__ uint32_t cur[1024];
  const int k = blockIdx.x, tid = threadIdx.x;
  const int lane = tid & 63, wv = tid >> 6;
  const int dbase = k << 10;
  int nd = N_NODES - dbase; if (nd > 1024) nd = 1024;
  if (tid < nd) cur[tid] = (uint32_t)row_ofs[dbase + tid];
  __syncthreads();
  for (int b = wv; b < DBLK; b += 16) {   // 16 waves; each owns 16 fragments
    uint32_t st = bofs_g[b * (NBKT + 1) + k];
    uint32_t en = bofs_g[b * (NBKT + 1) + k + 1];
    for (uint32_t i = st + lane; i < en; i += 64) {
      unsigned long long v = ebuf[(size_t)b * DCHUNK + i];
      int d = (int)(uint32_t)(v & 0xffffffffu);
      int s = (int)(uint32_t)(v >> 32);
      uint32_t slot = atomicAdd(&cur[d - dbase], 1u);
      csr[slot] = s;
    }
  }
}

// ---------------- W1t + Wt23 cast, single launch ----------------
__global__ void cast_w_k(const float* __restrict__ W1, const float* __restrict__ W2,
                         const float* __restrict__ W3, u16* __restrict__ W1t,
                         u16* __restrict__ Wt23) {
  int idx = blockIdx.x * blockDim.x + threadIdx.x;   // grid = (512*256 + 32*256)/256
  if (idx < IN_DIM * HID) {
    int k = idx >> 8, n = idx & 255;
    W1t[n * IN_DIM + k] = f2bf(W1[idx]);
  } else {
    int t = idx - IN_DIM * HID;
    int n = t >> 8, k = t & 255;
    float v = (n < 16) ? W2[k * NCLS + n] : W3[k * NCLS + (n - 16)];
    Wt23[n * HID + k] = f2bf(v);
  }
}

// ---------------- GEMM1 v3 (MFMA bf16): X1b = dropout1(x)*2*out_is @ W1, fused ----------------
#define G1_BM 128
#define G1_BKC 8   // chunks of 8 u16 (16 B) per row; BK = 64
__global__ __launch_bounds__(512, 2) void gemm1_k(
    const float* __restrict__ x, const float* __restrict__ out_is,
    uint32_t k0, uint32_t k1,
    const u16* __restrict__ W1t, u16* __restrict__ X1b) {
  __shared__ u16 As[G1_BM * 64];    // 16 KB, swizzled chunks
  __shared__ u16 Bs[256 * 64];      // 32 KB
  const int tid = threadIdx.x;
  const int wid = tid >> 6, lane = tid & 63;
  const int wr = wid >> 2, wc = wid & 3;     // wave tile: rows wr*64.., cols wc*64..
  const int m16 = lane & 15, q = lane >> 4;
  const int srow = lane >> 3, schunk = lane & 7;   // B staging: 8 rows x 8 chunks
  const long base_row = (long)blockIdx.x * G1_BM;

  const int arow_l = tid >> 2, acp = tid & 3;
  const long agrow = base_row + arow_l;
  const long asrow = (agrow < N_NODES) ? agrow : (N_NODES - 1);  // clamp (OOB rows unused)
  const float asc = 2.0f * out_is[asrow];
  const float* xrow = x + asrow * IN_DIM;
  const int aw0 = ((2 * acp)     ^ (arow_l & 7)) * 8;
  const int aw1 = ((2 * acp + 1) ^ (arow_l & 7)) * 8;

  float4v acc[4][4];
#pragma unroll
  for (int i = 0; i < 4; ++i)
#pragma unroll
    for (int j = 0; j < 4; ++j) acc[i][j] = (float4v)0.0f;

  for (int ks = 0; ks < IN_DIM / 64; ++ks) {
    const int kbase = ks * 64 + acp * 16;
    float4 f0 = *(const float4*)(xrow + kbase);
    float4 f1 = *(const float4*)(xrow + kbase + 4);
    float4 f2 = *(const float4*)(xrow + kbase + 8);
    float4 f3 = *(const float4*)(xrow + kbase + 12);
    float xv[16] = {f0.x, f0.y, f0.z, f0.w, f1.x, f1.y, f1.z, f1.w,
                    f2.x, f2.y, f2.z, f2.w, f3.x, f3.y, f3.z, f3.w};
    const uint32_t ibase = (uint32_t)asrow * IN_DIM + (uint32_t)kbase;
    u16 ob[16];
#pragma unroll
    for (int j = 0; j < 16; ++j) {
      uint32_t bits = tf_bits32(k0, k1, ibase + (uint32_t)j);
      ob[j] = f2bf((bits >> 31) ? 0.0f : xv[j] * asc);
    }
    uint4 pka, pkb;
    pka.x = (uint32_t)ob[0] | ((uint32_t)ob[1] << 16);
    pka.y = (uint32_t)ob[2] | ((uint32_t)ob[3] << 16);
    pka.z = (uint32_t)ob[4] | ((uint32_t)ob[5] << 16);
    pka.w = (uint32_t)ob[6] | ((uint32_t)ob[7] << 16);
    pkb.x = (uint32_t)ob[8] | ((uint32_t)ob[9] << 16);
    pkb.y = (uint32_t)ob[10] | ((uint32_t)ob[11] << 16);
    pkb.z = (uint32_t)ob[12] | ((uint32_t)ob[13] << 16);
    pkb.w = (uint32_t)ob[14] | ((uint32_t)ob[15] << 16);
    *(uint4*)(As + arow_l * 64 + aw0) = pka;
    *(uint4*)(As + arow_l * 64 + aw1) = pkb;
#pragma unroll
    for (int i = 0; i < 4; ++i) {
      int j = wid * 4 + i;
      int n = j * 8 + srow;
      int gch = ks * G1_BKC + (schunk ^ (n & 7));
      gload16(W1t + (size_t)n * IN_DIM + gch * 8, Bs + j * 512);
    }
    __syncthreads();
#pragma unroll
    for (int kk = 0; kk < 2; ++kk) {
      short8 a[4], b[4];
      const int kq = kk * 4 + q;
      const int c = kq ^ (m16 & 7);
#pragma unroll
      for (int rt = 0; rt < 4; ++rt) {
        int row = wr * 64 + rt * 16 + m16;
        a[rt] = *(const short8*)(As + row * 64 + c * 8);
      }
#pragma unroll
      for (int ct = 0; ct < 4; ++ct) {
        int n = wc * 64 + ct * 16 + m16;
        b[ct] = *(const short8*)(Bs + n * 64 + c * 8);
      }
#pragma unroll
      for (int rt = 0; rt < 4; ++rt)
#pragma unroll
        for (int ct = 0; ct < 4; ++ct)
          acc[rt][ct] = __builtin_amdgcn_mfma_f32_16x16x32_bf16(a[rt], b[ct], acc[rt][ct], 0, 0, 0);
    }
    __syncthreads();
  }
#pragma unroll
  for (int rt = 0; rt < 4; ++rt) {
#pragma unroll
    for (int r = 0; r < 4; ++r) {
      long grow = base_row + wr * 64 + rt * 16 + q * 4 + r;
      if (grow < N_NODES) {
#pragma unroll
        for (int ct = 0; ct < 4; ++ct)
          X1b[grow * HID + wc * 64 + ct * 16 + m16] = f2bf(acc[rt][ct][r]);
      }
    }
  }
}

// ---------------- CSR gather-sum (bf16) + relu -> h1 bf16 ----------------
__global__ __launch_bounds__(256) void agg_relu_k(
    const u16* __restrict__ X1b, const int* __restrict__ row_ofs,
    const int* __restrict__ csr, const float* __restrict__ in_is,
    u16* __restrict__ h1b) {
  int d = blockIdx.x * 4 + (threadIdx.x >> 6);  // exact: 25000*4 = N
  int lane = threadIdx.x & 63;
  int half = lane >> 5;
  int col = (lane & 31) * 8;
  int beg = row_ofs[d], end = row_ofs[d + 1];
  float a[8];
#pragma unroll
  for (int i = 0; i < 8; ++i) a[i] = 0.0f;
  int j = beg + half;
  for (; j + 14 < end; j += 16) {
    int s0 = csr[j],      s1 = csr[j + 2],  s2 = csr[j + 4],  s3 = csr[j + 6];
    int s4 = csr[j + 8],  s5 = csr[j + 10], s6 = csr[j + 12], s7 = csr[j + 14];
    uint4 v0 = *(const uint4*)(X1b + (size_t)s0 * HID + col);
    uint4 v1 = *(const uint4*)(X1b + (size_t)s1 * HID + col);
    uint4 v2 = *(const uint4*)(X1b + (size_t)s2 * HID + col);
    uint4 v3 = *(const uint4*)(X1b + (size_t)s3 * HID + col);
    uint4 v4 = *(const uint4*)(X1b + (size_t)s4 * HID + col);
    uint4 v5 = *(const uint4*)(X1b + (size_t)s5 * HID + col);
    uint4 v6 = *(const uint4*)(X1b + (size_t)s6 * HID + col);
    uint4 v7 = *(const uint4*)(X1b + (size_t)s7 * HID + col);
    acc8(a, v0); acc8(a, v1); acc8(a, v2); acc8(a, v3);
    acc8(a, v4); acc8(a, v5); acc8(a, v6); acc8(a, v7);
  }
  for (; j + 6 < end; j += 8) {
    int s0 = csr[j], s1 = csr[j + 2], s2 = csr[j + 4], s3 = csr[j + 6];
    uint4 v0 = *(const uint4*)(X1b + (size_t)s0 * HID + col);
    uint4 v1 = *(const uint4*)(X1b + (size_t)s1 * HID + col);
    uint4 v2 = *(const uint4*)(X1b + (size_t)s2 * HID + col);
    uint4 v3 = *(const uint4*)(X1b + (size_t)s3 * HID + col);
    acc8(a, v0); acc8(a, v1); acc8(a, v2); acc8(a, v3);
  }
  for (; j < end; j += 2) {
    uint4 v0 = *(const uint4*)(X1b + (size_t)csr[j] * HID + col);
    acc8(a, v0);
  }
#pragma unroll
  for (int i = 0; i < 8; ++i) a[i] += __shfl(a[i], lane ^ 32, 64);
  if (half == 0) {
    float is = in_is[d];
    u16 o[8];
#pragma unroll
    for (int i = 0; i < 8; ++i) o[i] = f2bf(fmaxf(a[i] * is, 0.0f));
    uint4 pk;
    pk.x = (uint32_t)o[0] | ((uint32_t)o[1] << 16);
    pk.y = (uint32_t)o[2] | ((uint32_t)o[3] << 16);
    pk.z = (uint32_t)o[4] | ((uint32_t)o[5] << 16);
    pk.w = (uint32_t)o[6] | ((uint32_t)o[7] << 16);
    *(uint4*)(h1b + (size_t)d * HID + col) = pk;
  }
}

// ---------------- BatchNorm stats (bf16 in, fp32 accumulate), vectorized ----------------
__global__ __launch_bounds__(256) void bn_stats_k(const u16* __restrict__ h1b,
                                                  float* __restrict__ bn) {
  __shared__ float ls[512];
  const int tid = threadIdx.x;
  const int cb = (tid & 31) * 8;   // col base
  const int ms = tid >> 5;         // row-stream 0..7
  float s[8], s2[8];
#pragma unroll
  for (int i = 0; i < 8; ++i) { s[i] = 0.f; s2[i] = 0.f; }
  for (int m = ms;; m += 8) {
    int r = blockIdx.x + 256 * m;
    if (r >= N_NODES) break;
    uint4 v = *(const uint4*)(h1b + (size_t)r * HID + cb);
    float f[8];
    f[0] = bf2f((u16)(v.x & 0xffffu)); f[1] = bf2f((u16)(v.x >> 16));
    f[2] = bf2f((u16)(v.y & 0xffffu)); f[3] = bf2f((u16)(v.y >> 16));
    f[4] = bf2f((u16)(v.z & 0xffffu)); f[5] = bf2f((u16)(v.z >> 16));
    f[6] = bf2f((u16)(v.w & 0xffffu)); f[7] = bf2f((u16)(v.w >> 16));
#pragma unroll
    for (int i = 0; i < 8; ++i) { s[i] += f[i]; s2[i] += f[i] * f[i]; }
  }
  ls[tid] = 0.f; ls[tid + 256] = 0.f;
  __syncthreads();
#pragma unroll
  for (int i = 0; i < 8; ++i) {
    atomicAdd(&ls[cb + i], s[i]);
    atomicAdd(&ls[256 + cb + i], s2[i]);
  }
  __syncthreads();
  atomicAdd(&bn[tid], ls[tid]);
  atomicAdd(&bn[HID + tid], ls[256 + tid]);
}

// ---------------- GEMM2/3 (MFMA), fused dropout-mask threefry + bn finalize ----------------
#define WLS 264   // u16 row stride for Wls: dword-stride 132 -> 2-way bank alias (free)
__global__ __launch_bounds__(256) void gemm23_k(
    const u16* __restrict__ h1b, const u16* __restrict__ Wt23,
    uint32_t ka0, uint32_t ka1, uint32_t kb0, uint32_t kb1,
    const float* __restrict__ out_is, const float* __restrict__ bn,
    u16* __restrict__ XMLV) {
  __shared__ u16 Wls[32 * WLS];
  __shared__ float cB[HID], cA[HID];
  const int tid = threadIdx.x;
#pragma unroll
  for (int i = 0; i < 4; ++i) {   // stage Wt23 (16KB) into padded LDS
    int idx = tid + i * 256;      // 1024 uint4 chunks
    int n = idx >> 5, c = idx & 31;
    *(uint4*)(Wls + n * WLS + c * 8) = ((const uint4*)Wt23)[idx];
  }
  {  // bn finalize: cB = istd, cA = -mean*istd
    float mean = bn[tid] * (1.0f / (float)N_NODES);
    float var = bn[HID + tid] * (1.0f / (float)N_NODES) - mean * mean;
    float istd = rsqrtf(var + 1e-5f);
    cB[tid] = istd;
    cA[tid] = -mean * istd;
  }
  __syncthreads();

  const int wv = tid >> 6, lane = tid & 63;
  const int m = lane & 15, q = lane >> 4;
  const long arow = (long)blockIdx.x * 64 + wv * 16 + m;   // A row this lane loads
  const bool valid = arow < N_NODES;
  const float osc = valid ? 2.0f * out_is[arow] : 0.0f;
  const uint32_t rbase = (uint32_t)(valid ? arow : 0) * HID;

  float4v accM = (float4v)0.0f, accL = (float4v)0.0f;
  for (int kc = 0; kc < HID; kc += 32) {
    const int kof = kc + q * 8;
    uint4 hv = make_uint4(0, 0, 0, 0);
    if (valid) hv = *(const uint4*)(h1b + arow * HID + kof);
    float4 B0 = *(const float4*)(cB + kof);
    float4 B1 = *(const float4*)(cB + kof + 4);
    float4 A0 = *(const float4*)(cA + kof);
    float4 A1 = *(const float4*)(cA + kof + 4);
    float hval[8] = {
      bf2f((u16)(hv.x & 0xffffu)), bf2f((u16)(hv.x >> 16)),
      bf2f((u16)(hv.y & 0xffffu)), bf2f((u16)(hv.y >> 16)),
      bf2f((u16)(hv.z & 0xffffu)), bf2f((u16)(hv.z >> 16)),
      bf2f((u16)(hv.w & 0xffffu)), bf2f((u16)(hv.w >> 16))};
    float nb[8] = {B0.x, B0.y, B0.z, B0.w, B1.x, B1.y, B1.z, B1.w};
    float na[8] = {A0.x, A0.y, A0.z, A0.w, A1.x, A1.y, A1.z, A1.w};
    const uint32_t ibase = rbase + (uint32_t)kof;
    short8 Aa, Ab;
#pragma unroll
    for (int jj = 0; jj < 8; ++jj) {
      float t = fmaf(hval[jj], nb[jj], na[jj]) * osc;
      u16 tb = f2bf(t);
      uint32_t ba = tf_bits32(ka0, ka1, ibase + (uint32_t)jj);   // dropout mask for mu
      uint32_t bb = tf_bits32(kb0, kb1, ibase + (uint32_t)jj);   // dropout mask for logvar
      Aa[jj] = (short)((ba >> 31) ? 0 : tb);
      Ab[jj] = (short)((bb >> 31) ? 0 : tb);
    }
    short8 Bm = *(const short8*)(Wls + m * WLS + kof);          // W2 col m
    short8 Bl = *(const short8*)(Wls + (16 + m) * WLS + kof);   // W3 col m
    accM = __builtin_amdgcn_mfma_f32_16x16x32_bf16(Aa, Bm, accM, 0, 0, 0);
    accL = __builtin_amdgcn_mfma_f32_16x16x32_bf16(Ab, Bl, accL, 0, 0, 0);
  }
#pragma unroll
  for (int r = 0; r < 4; ++r) {
    long srow = (long)blockIdx.x * 64 + wv * 16 + q * 4 + r;
    if (srow < N_NODES) {
      XMLV[srow * 32 + m]      = f2bf(accM[r]);
      XMLV[srow * 32 + 16 + m] = f2bf(accL[r]);
    }
  }
}

// ---------------- final: aggregate interleaved mu|logvar + reparameterize ----------------
__global__ __launch_bounds__(256) void agg_final_k(
    const u16* __restrict__ XMLV, const int* __restrict__ row_ofs,
    const int* __restrict__ csr, const float* __restrict__ in_is,
    uint32_t ke0, uint32_t ke1, float* __restrict__ out) {
  int g = blockIdx.x * 4 + (threadIdx.x >> 6);  // exact: 25000*4 = N
  int lane = threadIdx.x & 63;
  int half = lane >> 5, c = lane & 31;
  int beg = row_ofs[g], end = row_ofs[g + 1];
  float s = 0.f;
  int j = beg + half;
  for (; j + 14 < end; j += 16) {
    int s0 = csr[j],      s1 = csr[j + 2],  s2 = csr[j + 4],  s3 = csr[j + 6];
    int s4 = csr[j + 8],  s5 = csr[j + 10], s6 = csr[j + 12], s7 = csr[j + 14];
    float v0 = bf2f(XMLV[(size_t)s0 * 32 + c]);
    float v1 = bf2f(XMLV[(size_t)s1 * 32 + c]);
    float v2 = bf2f(XMLV[(size_t)s2 * 32 + c]);
    float v3 = bf2f(XMLV[(size_t)s3 * 32 + c]);
    float v4 = bf2f(XMLV[(size_t)s4 * 32 + c]);
    float v5 = bf2f(XMLV[(size_t)s5 * 32 + c]);
    float v6 = bf2f(XMLV[(size_t)s6 * 32 + c]);
    float v7 = bf2f(XMLV[(size_t)s7 * 32 + c]);
    s += v0; s += v1; s += v2; s += v3;
    s += v4; s += v5; s += v6; s += v7;
  }
#pragma unroll
  for (int k = 0; k < 8; ++k) {
    int e = j + 2 * k;
    if (e < end) s += bf2f(XMLV[(size_t)csr[e] * 32 + c]);
  }
  s += __shfl(s, lane ^ 32, 64);
  if (half == 0) {
    s *= in_is[g];
    float other = __shfl(s, lane ^ 16, 64);  // mu lane c gets logvar from lane c+16
    if (c < 16) {
      uint32_t i = (uint32_t)(g * NCLS + c);
      uint32_t bits = tf_bits32(ke0, ke1, i);
      float f = __uint_as_float((bits >> 9) | 0x3f800000u) - 1.0f;
      const float lo = -0.99999994f;          // nextafter(-1,0)
      float u = fmaxf(lo, fmaf(f, 2.0f, lo)); // (hi-lo) rounds to exactly 2.0f
      float eps = 1.41421356f * erfinv_f32(u);
      out[i] = eps * expf(other) + s;
    }
  }
}

// ---------------- host ----------------
extern "C" void kernel_launch(void* const* d_in, const int* in_sizes, int n_in,
                              void* d_out, int out_size, void* d_ws, size_t ws_size,
                              hipStream_t stream) {
  (void)in_sizes; (void)n_in; (void)out_size; (void)ws_size;
  const float* x  = (const float*)d_in[0];
  const float* W1 = (const float*)d_in[1];
  const float* W2 = (const float*)d_in[2];
  const float* W3 = (const float*)d_in[3];
  const int* esrc = (const int*)d_in[4];
  const int* edst = (const int*)d_in[5];
  float* out = (float*)d_out;

  uint32_t kb[8];
  for (int j = 0; j < 4; ++j)
    threefry2x32(0u, 42u, 0u, (uint32_t)j, kb[2 * j], kb[2 * j + 1]);
  // k1=(kb0,kb1) drop-x; k2a=(kb2,kb3); k2b=(kb4,kb5); keps=(kb6,kb7)

  char* p = (char*)d_ws;
  auto take = [&](size_t bytes) -> void* {
    void* r = (void*)p;
    p += (bytes + 255) & ~(size_t)255;
    return r;
  };
  unsigned long long* ebuf = (unsigned long long*)take(sizeof(unsigned long long) * (size_t)N_EDGES); // 25.6 MB
  u16* X1b       = (u16*)take(sizeof(u16) * (size_t)N_NODES * HID);
  u16* h1b       = (u16*)take(sizeof(u16) * (size_t)N_NODES * HID);
  u16* XMLV      = (u16*)take(sizeof(u16) * (size_t)N_NODES * 32);
  u16* W1t       = (u16*)take(sizeof(u16) * (size_t)IN_DIM * HID);
  u16* Wt23      = (u16*)take(sizeof(u16) * 32 * HID);
  uint32_t* deg  = (uint32_t*)take(sizeof(uint32_t) * 2 * N_NODES);      // out | in
  uint32_t* bofs_g = (uint32_t*)take(sizeof(uint32_t) * (size_t)DBLK * (NBKT + 1));
  int* tile_sum  = (int*)take(sizeof(int) * NTILE);
  float* out_is  = (float*)take(sizeof(float) * N_NODES);
  float* in_is   = (float*)take(sizeof(float) * N_NODES);
  int* row_ofs   = (int*)take(sizeof(int) * (N_NODES + 1));
  int* csr       = (int*)take(sizeof(int) * N_EDGES);
  float* bn      = (float*)take(sizeof(float) * 1024);

  hipMemsetAsync(bn, 0, sizeof(float) * 512, stream);
  hipMemsetAsync(deg, 0, sizeof(uint32_t) * 2 * N_NODES, stream);

  prep1_k<<<DBLK, 1024, 0, stream>>>(esrc, edst, deg, bofs_g, ebuf);
  scan1_k<<<NTILE, 256, 0, stream>>>(deg, out_is, in_is, row_ofs, tile_sum);
  fixup_k<<<NTILE, 256, 0, stream>>>(tile_sum, row_ofs);
  bplace_k<<<NBKT, 1024, 0, stream>>>(ebuf, bofs_g, row_ofs, csr);

  cast_w_k<<<(IN_DIM * HID + 32 * HID) / 256, 256, 0, stream>>>(W1, W2, W3, W1t, Wt23);

  gemm1_k<<<(N_NODES + G1_BM - 1) / G1_BM, 512, 0, stream>>>(x, out_is, kb[0], kb[1], W1t, X1b);
  agg_relu_k<<<N_NODES / 4, 256, 0, stream>>>(X1b, row_ofs, csr, in_is, h1b);
  bn_stats_k<<<256, 256, 0, stream>>>(h1b, bn);
  gemm23_k<<<(N_NODES + 63) / 64, 256, 0, stream>>>(h1b, Wt23, kb[2], kb[3], kb[4], kb[5],
                                                    out_is, bn, XMLV);
  agg_final_k<<<N_NODES / 4, 256, 0, stream>>>(XMLV, row_ofs, csr, in_is, kb[6], kb[7], out);
}

// Round 9
// 908.830 us; speedup vs baseline: 1.2284x; 1.2284x over previous
//
#include <hip/hip_runtime.h>
#include <stdint.h>

#define N_NODES 100000
#define N_EDGES 3200000
#define IN_DIM  512
#define HID     256
#define NCLS    16

// graph-prep geometry
#define DBLK   256                   // blocks (one per CU)
#define DCHUNK (N_EDGES / DBLK)      // 12500 edges per block
#define DWIN2  50000                 // nodes per LDS window in hist (byte counters, 100 KB)
#define NBKT   98                    // dst buckets of 1024 nodes  ((N_NODES+1023)>>10)
#define NTILE  ((N_NODES + 255) / 256)   // 391 scan tiles

typedef unsigned short u16;
typedef __attribute__((ext_vector_type(8))) short short8;
typedef __attribute__((ext_vector_type(4))) float float4v;

// ---------------- bf16 helpers ----------------
__device__ __forceinline__ float bf2f(u16 u) {
  return __uint_as_float(((uint32_t)u) << 16);
}
__device__ __forceinline__ u16 f2bf(float f) {   // round-to-nearest-even
  uint32_t u = __float_as_uint(f);
  return (u16)((u + 0x7fffu + ((u >> 16) & 1u)) >> 16);
}
__device__ __forceinline__ void acc8(float* a, uint4 v) {
  a[0] += bf2f((u16)(v.x & 0xffffu)); a[1] += bf2f((u16)(v.x >> 16));
  a[2] += bf2f((u16)(v.y & 0xffffu)); a[3] += bf2f((u16)(v.y >> 16));
  a[4] += bf2f((u16)(v.z & 0xffffu)); a[5] += bf2f((u16)(v.z >> 16));
  a[6] += bf2f((u16)(v.w & 0xffffu)); a[7] += bf2f((u16)(v.w >> 16));
}

// async global->LDS, 16B per lane: LDS dest = wave-uniform base + lane*16
__device__ __forceinline__ void gload16(const void* g, void* l) {
  __builtin_amdgcn_global_load_lds(
      (const __attribute__((address_space(1))) uint32_t*)g,
      (__attribute__((address_space(3))) uint32_t*)l, 16, 0, 0);
}

// ---------------- Threefry-2x32 (exact JAX schedule, partitionable mode) ----------------
__host__ __device__ __forceinline__ uint32_t rotl32(uint32_t v, int d) {
  return (v << d) | (v >> (32 - d));
}

__host__ __device__ __forceinline__ void threefry2x32(uint32_t k0, uint32_t k1,
    uint32_t x0, uint32_t x1, uint32_t& o0, uint32_t& o1) {
  uint32_t ks0 = k0, ks1 = k1, ks2 = k0 ^ k1 ^ 0x1BD11BDAu;
  x0 += ks0; x1 += ks1;
#define TF_R(r) { x0 += x1; x1 = rotl32(x1, r); x1 ^= x0; }
  TF_R(13) TF_R(15) TF_R(26) TF_R(6)
  x0 += ks1; x1 += ks2 + 1u;
  TF_R(17) TF_R(29) TF_R(16) TF_R(24)
  x0 += ks2; x1 += ks0 + 2u;
  TF_R(13) TF_R(15) TF_R(26) TF_R(6)
  x0 += ks0; x1 += ks1 + 3u;
  TF_R(17) TF_R(29) TF_R(16) TF_R(24)
  x0 += ks1; x1 += ks2 + 4u;
  TF_R(13) TF_R(15) TF_R(26) TF_R(6)
  x0 += ks2; x1 += ks0 + 5u;
#undef TF_R
  o0 = x0; o1 = x1;
}

__host__ __device__ __forceinline__ uint32_t tf_bits32(uint32_t k0, uint32_t k1, uint32_t idx) {
  uint32_t o0, o1;
  threefry2x32(k0, k1, 0u, idx, o0, o1);
  return o0 ^ o1;
}

// ---------------- erfinv: XLA/Giles f32 polynomial ----------------
__device__ __forceinline__ float erfinv_f32(float x) {
  float w = -log1pf(-x * x);
  float p;
  if (w < 5.0f) {
    w -= 2.5f;
    p = 2.81022636e-08f;
    p = fmaf(p, w, 3.43273939e-07f);
    p = fmaf(p, w, -3.5233877e-06f);
    p = fmaf(p, w, -4.39150654e-06f);
    p = fmaf(p, w, 0.00021858087f);
    p = fmaf(p, w, -0.00125372503f);
    p = fmaf(p, w, -0.00417768164f);
    p = fmaf(p, w, 0.246640727f);
    p = fmaf(p, w, 1.50140941f);
  } else {
    w = sqrtf(w) - 3.0f;
    p = -0.000200214257f;
    p = fmaf(p, w, 0.000100950558f);
    p = fmaf(p, w, 0.00134934322f);
    p = fmaf(p, w, -0.00367342844f);
    p = fmaf(p, w, 0.00573950773f);
    p = fmaf(p, w, -0.0076224613f);
    p = fmaf(p, w, 0.00943887047f);
    p = fmaf(p, w, 1.00167406f);
    p = fmaf(p, w, 2.83297682f);
  }
  return p * x;
}

// ---------------- hist+partition: privatized histogram + bucket-sort, one kernel ----------------
// P16[b][node] u16: lo8 = out-count, hi8 = in-count of block b's edge chunk.
// bofs_g[b][k]: exclusive prefix of block b's bucket-k edge count.
// Tail: bucket-partition this block's chunk into its private ebuf region
// (100 KB window, L2-resident writes; edge chunk re-read L2-warm).
__global__ __launch_bounds__(1024) void hist_part_k(
    const int* __restrict__ esrc, const int* __restrict__ edst,
    u16* __restrict__ P16, uint32_t* __restrict__ bofs_g,
    unsigned long long* __restrict__ ebuf) {
  __shared__ uint32_t h32[DWIN2 / 2];   // 25000 u32 = 100 KB, 2 nodes per word
  __shared__ uint32_t bcnt[NBKT + 1];
  const int b = blockIdx.x, tid = threadIdx.x;
  const int ebase = b * DCHUNK;
  if (tid < NBKT + 1) bcnt[tid] = 0u;
  for (int w = 0; w < 2; ++w) {
    const int lo = w * DWIN2;
    for (int i = tid; i < DWIN2 / 2; i += 1024) h32[i] = 0u;
    __syncthreads();
    for (int e = ebase + tid; e < ebase + DCHUNK; e += 1024) {
      int s = esrc[e], d = edst[e];
      unsigned su = (unsigned)(s - lo);
      if (su < (unsigned)DWIN2) atomicAdd(&h32[su >> 1], 1u << ((su & 1) * 16));
      unsigned du = (unsigned)(d - lo);
      if (du < (unsigned)DWIN2) atomicAdd(&h32[du >> 1], 0x100u << ((du & 1) * 16));
      if (w == 0) atomicAdd(&bcnt[d >> 10], 1u);
    }
    __syncthreads();
    for (int i = tid; i < DWIN2 / 2; i += 1024) {
      // word: [out_even | in_even<<8 | out_odd<<16 | in_odd<<24] == two P16 entries
      *(uint32_t*)(P16 + (size_t)b * N_NODES + lo + 2 * i) = h32[i];
    }
    __syncthreads();
  }
  if (tid == 0) {   // exclusive scan of 98 bucket counts
    uint32_t run = 0;
    for (int k = 0; k < NBKT; ++k) { uint32_t c = bcnt[k]; bcnt[k] = run; run += c; }
    bcnt[NBKT] = run;   // == DCHUNK
  }
  __syncthreads();
  if (tid < NBKT + 1) bofs_g[b * (NBKT + 1) + tid] = bcnt[tid];
  __syncthreads();
  // bucket partition (bcnt now serves as cursors); edge chunk is L2-warm
  for (int e = ebase + tid; e < ebase + DCHUNK; e += 1024) {
    int d = edst[e], s = esrc[e];
    uint32_t slot = atomicAdd(&bcnt[d >> 10], 1u);
    ebuf[(size_t)b * DCHUNK + slot] = ((unsigned long long)(uint32_t)s << 32) | (uint32_t)d;
  }
}

// ---------------- degsum: degrees + inv-sqrt + intra-tile exclusive scan of in-degree ----------------
__global__ void degsum_k(const u16* __restrict__ P16, float* __restrict__ out_is,
                         float* __restrict__ in_is, int* __restrict__ row_ofs,
                         int* __restrict__ tile_sum) {
  const int tid = threadIdx.x;
  const int n = blockIdx.x * 256 + tid;
  const int lane = tid & 63, wv = tid >> 6;
  uint32_t to = 0, ti = 0;
  if (n < N_NODES) {
#pragma unroll 8
    for (int b = 0; b < DBLK; ++b) {
      uint32_t v = P16[(size_t)b * N_NODES + n];
      to += v & 0xffu; ti += v >> 8;
    }
    out_is[n] = rsqrtf(fmaxf((float)to, 1.0f));
    in_is[n]  = rsqrtf(fmaxf((float)ti, 1.0f));
  }
  int sc = (int)ti;
#pragma unroll
  for (int d = 1; d < 64; d <<= 1) {
    int t = __shfl_up(sc, d, 64);
    if (lane >= d) sc += t;
  }
  __shared__ int ws[4];
  if (lane == 63) ws[wv] = sc;
  __syncthreads();
  int wbase = 0;
#pragma unroll
  for (int i = 0; i < 4; ++i) if (i < wv) wbase += ws[i];
  if (n < N_NODES) row_ofs[n] = wbase + sc - (int)ti;   // tile-local exclusive prefix
  if (tid == 0) tile_sum[blockIdx.x] = ws[0] + ws[1] + ws[2] + ws[3];
}

// ---------------- fixup: add tile bases (parallel over tiles) ----------------
__global__ void fixup_k(const int* __restrict__ tile_sum, int* __restrict__ row_ofs) {
  const int b = blockIdx.x, tid = threadIdx.x;
  const int lane = tid & 63, wv = tid >> 6;
  int v = 0;
  if (tid < b) v = tile_sum[tid];
  if (tid + 256 < b) v += tile_sum[tid + 256];
#pragma unroll
  for (int m = 1; m < 64; m <<= 1) v += __shfl_xor(v, m, 64);
  __shared__ int wr[4];
  if (lane == 0) wr[wv] = v;
  __syncthreads();
  const int base = wr[0] + wr[1] + wr[2] + wr[3];
  const int n = b * 256 + tid;
  if (n < N_NODES) row_ofs[n] += base;
  if (b == (int)gridDim.x - 1 && tid == 0) row_ofs[N_NODES] = base + tile_sum[b];
}

// ---------------- bplace: per-bucket scatter to final CSR slots (L2-local) ----------------
__global__ __launch_bounds__(1024) void bplace_k(
    const unsigned long long* __restrict__ ebuf, const uint32_t* __restrict__ bofs_g,
    const int* __restrict__ row_ofs, int* __restrict__ csr) {
  __shared__ uint32_t cur[1024];
  const int k = blockIdx.x, tid = threadIdx.x;
  const int lane = tid & 63, wv = tid >> 6;
  const int dbase = k << 10;
  int nd = N_NODES - dbase; if (nd > 1024) nd = 1024;
  if (tid < nd) cur[tid] = (uint32_t)row_ofs[dbase + tid];
  __syncthreads();
  for (int b = wv; b < DBLK; b += 16) {   // 16 waves; each owns 16 fragments
    uint32_t st = bofs_g[b * (NBKT + 1) + k];
    uint32_t en = bofs_g[b * (NBKT + 1) + k + 1];
    for (uint32_t i = st + lane; i < en; i += 64) {
      unsigned long long v = ebuf[(size_t)b * DCHUNK + i];
      int d = (int)(uint32_t)(v & 0xffffffffu);
      int s = (int)(uint32_t)(v >> 32);
      uint32_t slot = atomicAdd(&cur[d - dbase], 1u);
      csr[slot] = s;
    }
  }
}

// ---------------- W1t + Wt23 cast, single launch ----------------
__global__ void cast_w_k(const float* __restrict__ W1, const float* __restrict__ W2,
                         const float* __restrict__ W3, u16* __restrict__ W1t,
                         u16* __restrict__ Wt23) {
  int idx = blockIdx.x * blockDim.x + threadIdx.x;   // grid = (512*256 + 32*256)/256
  if (idx < IN_DIM * HID) {
    int k = idx >> 8, n = idx & 255;
    W1t[n * IN_DIM + k] = f2bf(W1[idx]);
  } else {
    int t = idx - IN_DIM * HID;
    int n = t >> 8, k = t & 255;
    float v = (n < 16) ? W2[k * NCLS + n] : W3[k * NCLS + (n - 16)];
    Wt23[n * HID + k] = f2bf(v);
  }
}

// ---------------- GEMM1 v3 (MFMA bf16): X1b = dropout1(x)*2*out_is @ W1, fused ----------------
#define G1_BM 128
#define G1_BKC 8   // chunks of 8 u16 (16 B) per row; BK = 64
__global__ __launch_bounds__(512, 2) void gemm1_k(
    const float* __restrict__ x, const float* __restrict__ out_is,
    uint32_t k0, uint32_t k1,
    const u16* __restrict__ W1t, u16* __restrict__ X1b) {
  __shared__ u16 As[G1_BM * 64];    // 16 KB, swizzled chunks
  __shared__ u16 Bs[256 * 64];      // 32 KB
  const int tid = threadIdx.x;
  const int wid = tid >> 6, lane = tid & 63;
  const int wr = wid >> 2, wc = wid & 3;     // wave tile: rows wr*64.., cols wc*64..
  const int m16 = lane & 15, q = lane >> 4;
  const int srow = lane >> 3, schunk = lane & 7;   // B staging: 8 rows x 8 chunks
  const long base_row = (long)blockIdx.x * G1_BM;

  const int arow_l = tid >> 2, acp = tid & 3;
  const long agrow = base_row + arow_l;
  const long asrow = (agrow < N_NODES) ? agrow : (N_NODES - 1);  // clamp (OOB rows unused)
  const float asc = 2.0f * out_is[asrow];
  const float* xrow = x + asrow * IN_DIM;
  const int aw0 = ((2 * acp)     ^ (arow_l & 7)) * 8;
  const int aw1 = ((2 * acp + 1) ^ (arow_l & 7)) * 8;

  float4v acc[4][4];
#pragma unroll
  for (int i = 0; i < 4; ++i)
#pragma unroll
    for (int j = 0; j < 4; ++j) acc[i][j] = (float4v)0.0f;

  for (int ks = 0; ks < IN_DIM / 64; ++ks) {
    const int kbase = ks * 64 + acp * 16;
    float4 f0 = *(const float4*)(xrow + kbase);
    float4 f1 = *(const float4*)(xrow + kbase + 4);
    float4 f2 = *(const float4*)(xrow + kbase + 8);
    float4 f3 = *(const float4*)(xrow + kbase + 12);
    float xv[16] = {f0.x, f0.y, f0.z, f0.w, f1.x, f1.y, f1.z, f1.w,
                    f2.x, f2.y, f2.z, f2.w, f3.x, f3.y, f3.z, f3.w};
    const uint32_t ibase = (uint32_t)asrow * IN_DIM + (uint32_t)kbase;
    u16 ob[16];
#pragma unroll
    for (int j = 0; j < 16; ++j) {
      uint32_t bits = tf_bits32(k0, k1, ibase + (uint32_t)j);
      ob[j] = f2bf((bits >> 31) ? 0.0f : xv[j] * asc);
    }
    uint4 pka, pkb;
    pka.x = (uint32_t)ob[0] | ((uint32_t)ob[1] << 16);
    pka.y = (uint32_t)ob[2] | ((uint32_t)ob[3] << 16);
    pka.z = (uint32_t)ob[4] | ((uint32_t)ob[5] << 16);
    pka.w = (uint32_t)ob[6] | ((uint32_t)ob[7] << 16);
    pkb.x = (uint32_t)ob[8] | ((uint32_t)ob[9] << 16);
    pkb.y = (uint32_t)ob[10] | ((uint32_t)ob[11] << 16);
    pkb.z = (uint32_t)ob[12] | ((uint32_t)ob[13] << 16);
    pkb.w = (uint32_t)ob[14] | ((uint32_t)ob[15] << 16);
    *(uint4*)(As + arow_l * 64 + aw0) = pka;
    *(uint4*)(As + arow_l * 64 + aw1) = pkb;
#pragma unroll
    for (int i = 0; i < 4; ++i) {
      int j = wid * 4 + i;
      int n = j * 8 + srow;
      int gch = ks * G1_BKC + (schunk ^ (n & 7));
      gload16(W1t + (size_t)n * IN_DIM + gch * 8, Bs + j * 512);
    }
    __syncthreads();
#pragma unroll
    for (int kk = 0; kk < 2; ++kk) {
      short8 a[4], b[4];
      const int kq = kk * 4 + q;
      const int c = kq ^ (m16 & 7);
#pragma unroll
      for (int rt = 0; rt < 4; ++rt) {
        int row = wr * 64 + rt * 16 + m16;
        a[rt] = *(const short8*)(As + row * 64 + c * 8);
      }
#pragma unroll
      for (int ct = 0; ct < 4; ++ct) {
        int n = wc * 64 + ct * 16 + m16;
        b[ct] = *(const short8*)(Bs + n * 64 + c * 8);
      }
#pragma unroll
      for (int rt = 0; rt < 4; ++rt)
#pragma unroll
        for (int ct = 0; ct < 4; ++ct)
          acc[rt][ct] = __builtin_amdgcn_mfma_f32_16x16x32_bf16(a[rt], b[ct], acc[rt][ct], 0, 0, 0);
    }
    __syncthreads();
  }
#pragma unroll
  for (int rt = 0; rt < 4; ++rt) {
#pragma unroll
    for (int r = 0; r < 4; ++r) {
      long grow = base_row + wr * 64 + rt * 16 + q * 4 + r;
      if (grow < N_NODES) {
#pragma unroll
        for (int ct = 0; ct < 4; ++ct)
          X1b[grow * HID + wc * 64 + ct * 16 + m16] = f2bf(acc[rt][ct][r]);
      }
    }
  }
}

// ---------------- CSR gather-sum (bf16) + relu -> h1 bf16 ----------------
__global__ __launch_bounds__(256) void agg_relu_k(
    const u16* __restrict__ X1b, const int* __restrict__ row_ofs,
    const int* __restrict__ csr, const float* __restrict__ in_is,
    u16* __restrict__ h1b) {
  int d = blockIdx.x * 4 + (threadIdx.x >> 6);  // exact: 25000*4 = N
  int lane = threadIdx.x & 63;
  int half = lane >> 5;
  int col = (lane & 31) * 8;
  int beg = row_ofs[d], end = row_ofs[d + 1];
  float a[8];
#pragma unroll
  for (int i = 0; i < 8; ++i) a[i] = 0.0f;
  int j = beg + half;
  for (; j + 14 < end; j += 16) {
    int s0 = csr[j],      s1 = csr[j + 2],  s2 = csr[j + 4],  s3 = csr[j + 6];
    int s4 = csr[j + 8],  s5 = csr[j + 10], s6 = csr[j + 12], s7 = csr[j + 14];
    uint4 v0 = *(const uint4*)(X1b + (size_t)s0 * HID + col);
    uint4 v1 = *(const uint4*)(X1b + (size_t)s1 * HID + col);
    uint4 v2 = *(const uint4*)(X1b + (size_t)s2 * HID + col);
    uint4 v3 = *(const uint4*)(X1b + (size_t)s3 * HID + col);
    uint4 v4 = *(const uint4*)(X1b + (size_t)s4 * HID + col);
    uint4 v5 = *(const uint4*)(X1b + (size_t)s5 * HID + col);
    uint4 v6 = *(const uint4*)(X1b + (size_t)s6 * HID + col);
    uint4 v7 = *(const uint4*)(X1b + (size_t)s7 * HID + col);
    acc8(a, v0); acc8(a, v1); acc8(a, v2); acc8(a, v3);
    acc8(a, v4); acc8(a, v5); acc8(a, v6); acc8(a, v7);
  }
  for (; j + 6 < end; j += 8) {
    int s0 = csr[j], s1 = csr[j + 2], s2 = csr[j + 4], s3 = csr[j + 6];
    uint4 v0 = *(const uint4*)(X1b + (size_t)s0 * HID + col);
    uint4 v1 = *(const uint4*)(X1b + (size_t)s1 * HID + col);
    uint4 v2 = *(const uint4*)(X1b + (size_t)s2 * HID + col);
    uint4 v3 = *(const uint4*)(X1b + (size_t)s3 * HID + col);
    acc8(a, v0); acc8(a, v1); acc8(a, v2); acc8(a, v3);
  }
  for (; j < end; j += 2) {
    uint4 v0 = *(const uint4*)(X1b + (size_t)csr[j] * HID + col);
    acc8(a, v0);
  }
#pragma unroll
  for (int i = 0; i < 8; ++i) a[i] += __shfl(a[i], lane ^ 32, 64);
  if (half == 0) {
    float is = in_is[d];
    u16 o[8];
#pragma unroll
    for (int i = 0; i < 8; ++i) o[i] = f2bf(fmaxf(a[i] * is, 0.0f));
    uint4 pk;
    pk.x = (uint32_t)o[0] | ((uint32_t)o[1] << 16);
    pk.y = (uint32_t)o[2] | ((uint32_t)o[3] << 16);
    pk.z = (uint32_t)o[4] | ((uint32_t)o[5] << 16);
    pk.w = (uint32_t)o[6] | ((uint32_t)o[7] << 16);
    *(uint4*)(h1b + (size_t)d * HID + col) = pk;
  }
}

// ---------------- BatchNorm stats (bf16 in, fp32 accumulate), vectorized ----------------
__global__ __launch_bounds__(256) void bn_stats_k(const u16* __restrict__ h1b,
                                                  float* __restrict__ bn) {
  __shared__ float ls[512];
  const int tid = threadIdx.x;
  const int cb = (tid & 31) * 8;   // col base
  const int ms = tid >> 5;         // row-stream 0..7
  float s[8], s2[8];
#pragma unroll
  for (int i = 0; i < 8; ++i) { s[i] = 0.f; s2[i] = 0.f; }
  for (int m = ms;; m += 8) {
    int r = blockIdx.x + 256 * m;
    if (r >= N_NODES) break;
    uint4 v = *(const uint4*)(h1b + (size_t)r * HID + cb);
    float f[8];
    f[0] = bf2f((u16)(v.x & 0xffffu)); f[1] = bf2f((u16)(v.x >> 16));
    f[2] = bf2f((u16)(v.y & 0xffffu)); f[3] = bf2f((u16)(v.y >> 16));
    f[4] = bf2f((u16)(v.z & 0xffffu)); f[5] = bf2f((u16)(v.z >> 16));
    f[6] = bf2f((u16)(v.w & 0xffffu)); f[7] = bf2f((u16)(v.w >> 16));
#pragma unroll
    for (int i = 0; i < 8; ++i) { s[i] += f[i]; s2[i] += f[i] * f[i]; }
  }
  ls[tid] = 0.f; ls[tid + 256] = 0.f;
  __syncthreads();
#pragma unroll
  for (int i = 0; i < 8; ++i) {
    atomicAdd(&ls[cb + i], s[i]);
    atomicAdd(&ls[256 + cb + i], s2[i]);
  }
  __syncthreads();
  atomicAdd(&bn[tid], ls[tid]);
  atomicAdd(&bn[HID + tid], ls[256 + tid]);
}

// ---------------- GEMM2/3 (MFMA), fused dropout-mask threefry + bn finalize ----------------
#define WLS 264   // u16 row stride for Wls: dword-stride 132 -> 2-way bank alias (free)
__global__ __launch_bounds__(256) void gemm23_k(
    const u16* __restrict__ h1b, const u16* __restrict__ Wt23,
    uint32_t ka0, uint32_t ka1, uint32_t kb0, uint32_t kb1,
    const float* __restrict__ out_is, const float* __restrict__ bn,
    u16* __restrict__ XMLV) {
  __shared__ u16 Wls[32 * WLS];
  __shared__ float cB[HID], cA[HID];
  const int tid = threadIdx.x;
#pragma unroll
  for (int i = 0; i < 4; ++i) {   // stage Wt23 (16KB) into padded LDS
    int idx = tid + i * 256;      // 1024 uint4 chunks
    int n = idx >> 5, c = idx & 31;
    *(uint4*)(Wls + n * WLS + c * 8) = ((const uint4*)Wt23)[idx];
  }
  {  // bn finalize: cB = istd, cA = -mean*istd
    float mean = bn[tid] * (1.0f / (float)N_NODES);
    float var = bn[HID + tid] * (1.0f / (float)N_NODES) - mean * mean;
    float istd = rsqrtf(var + 1e-5f);
    cB[tid] = istd;
    cA[tid] = -mean * istd;
  }
  __syncthreads();

  const int wv = tid >> 6, lane = tid & 63;
  const int m = lane & 15, q = lane >> 4;
  const long arow = (long)blockIdx.x * 64 + wv * 16 + m;   // A row this lane loads
  const bool valid = arow < N_NODES;
  const float osc = valid ? 2.0f * out_is[arow] : 0.0f;
  const uint32_t rbase = (uint32_t)(valid ? arow : 0) * HID;

  float4v accM = (float4v)0.0f, accL = (float4v)0.0f;
  for (int kc = 0; kc < HID; kc += 32) {
    const int kof = kc + q * 8;
    uint4 hv = make_uint4(0, 0, 0, 0);
    if (valid) hv = *(const uint4*)(h1b + arow * HID + kof);
    float4 B0 = *(const float4*)(cB + kof);
    float4 B1 = *(const float4*)(cB + kof + 4);
    float4 A0 = *(const float4*)(cA + kof);
    float4 A1 = *(const float4*)(cA + kof + 4);
    float hval[8] = {
      bf2f((u16)(hv.x & 0xffffu)), bf2f((u16)(hv.x >> 16)),
      bf2f((u16)(hv.y & 0xffffu)), bf2f((u16)(hv.y >> 16)),
      bf2f((u16)(hv.z & 0xffffu)), bf2f((u16)(hv.z >> 16)),
      bf2f((u16)(hv.w & 0xffffu)), bf2f((u16)(hv.w >> 16))};
    float nb[8] = {B0.x, B0.y, B0.z, B0.w, B1.x, B1.y, B1.z, B1.w};
    float na[8] = {A0.x, A0.y, A0.z, A0.w, A1.x, A1.y, A1.z, A1.w};
    const uint32_t ibase = rbase + (uint32_t)kof;
    short8 Aa, Ab;
#pragma unroll
    for (int jj = 0; jj < 8; ++jj) {
      float t = fmaf(hval[jj], nb[jj], na[jj]) * osc;
      u16 tb = f2bf(t);
      uint32_t ba = tf_bits32(ka0, ka1, ibase + (uint32_t)jj);   // dropout mask for mu
      uint32_t bb = tf_bits32(kb0, kb1, ibase + (uint32_t)jj);   // dropout mask for logvar
      Aa[jj] = (short)((ba >> 31) ? 0 : tb);
      Ab[jj] = (short)((bb >> 31) ? 0 : tb);
    }
    short8 Bm = *(const short8*)(Wls + m * WLS + kof);          // W2 col m
    short8 Bl = *(const short8*)(Wls + (16 + m) * WLS + kof);   // W3 col m
    accM = __builtin_amdgcn_mfma_f32_16x16x32_bf16(Aa, Bm, accM, 0, 0, 0);
    accL = __builtin_amdgcn_mfma_f32_16x16x32_bf16(Ab, Bl, accL, 0, 0, 0);
  }
#pragma unroll
  for (int r = 0; r < 4; ++r) {
    long srow = (long)blockIdx.x * 64 + wv * 16 + q * 4 + r;
    if (srow < N_NODES) {
      XMLV[srow * 32 + m]      = f2bf(accM[r]);
      XMLV[srow * 32 + 16 + m] = f2bf(accL[r]);
    }
  }
}

// ---------------- final: aggregate interleaved mu|logvar + reparameterize ----------------
__global__ __launch_bounds__(256) void agg_final_k(
    const u16* __restrict__ XMLV, const int* __restrict__ row_ofs,
    const int* __restrict__ csr, const float* __restrict__ in_is,
    uint32_t ke0, uint32_t ke1, float* __restrict__ out) {
  int g = blockIdx.x * 4 + (threadIdx.x >> 6);  // exact: 25000*4 = N
  int lane = threadIdx.x & 63;
  int half = lane >> 5, c = lane & 31;
  int beg = row_ofs[g], end = row_ofs[g + 1];
  float s = 0.f;
  int j = beg + half;
  for (; j + 14 < end; j += 16) {
    int s0 = csr[j],      s1 = csr[j + 2],  s2 = csr[j + 4],  s3 = csr[j + 6];
    int s4 = csr[j + 8],  s5 = csr[j + 10], s6 = csr[j + 12], s7 = csr[j + 14];
    float v0 = bf2f(XMLV[(size_t)s0 * 32 + c]);
    float v1 = bf2f(XMLV[(size_t)s1 * 32 + c]);
    float v2 = bf2f(XMLV[(size_t)s2 * 32 + c]);
    float v3 = bf2f(XMLV[(size_t)s3 * 32 + c]);
    float v4 = bf2f(XMLV[(size_t)s4 * 32 + c]);
    float v5 = bf2f(XMLV[(size_t)s5 * 32 + c]);
    float v6 = bf2f(XMLV[(size_t)s6 * 32 + c]);
    float v7 = bf2f(XMLV[(size_t)s7 * 32 + c]);
    s += v0; s += v1; s += v2; s += v3;
    s += v4; s += v5; s += v6; s += v7;
  }
#pragma unroll
  for (int k = 0; k < 8; ++k) {
    int e = j + 2 * k;
    if (e < end) s += bf2f(XMLV[(size_t)csr[e] * 32 + c]);
  }
  s += __shfl(s, lane ^ 32, 64);
  if (half == 0) {
    s *= in_is[g];
    float other = __shfl(s, lane ^ 16, 64);  // mu lane c gets logvar from lane c+16
    if (c < 16) {
      uint32_t i = (uint32_t)(g * NCLS + c);
      uint32_t bits = tf_bits32(ke0, ke1, i);
      float f = __uint_as_float((bits >> 9) | 0x3f800000u) - 1.0f;
      const float lo = -0.99999994f;          // nextafter(-1,0)
      float u = fmaxf(lo, fmaf(f, 2.0f, lo)); // (hi-lo) rounds to exactly 2.0f
      float eps = 1.41421356f * erfinv_f32(u);
      out[i] = eps * expf(other) + s;
    }
  }
}

// ---------------- host ----------------
extern "C" void kernel_launch(void* const* d_in, const int* in_sizes, int n_in,
                              void* d_out, int out_size, void* d_ws, size_t ws_size,
                              hipStream_t stream) {
  (void)in_sizes; (void)n_in; (void)out_size; (void)ws_size;
  const float* x  = (const float*)d_in[0];
  const float* W1 = (const float*)d_in[1];
  const float* W2 = (const float*)d_in[2];
  const float* W3 = (const float*)d_in[3];
  const int* esrc = (const int*)d_in[4];
  const int* edst = (const int*)d_in[5];
  float* out = (float*)d_out;

  uint32_t kb[8];
  for (int j = 0; j < 4; ++j)
    threefry2x32(0u, 42u, 0u, (uint32_t)j, kb[2 * j], kb[2 * j + 1]);
  // k1=(kb0,kb1) drop-x; k2a=(kb2,kb3); k2b=(kb4,kb5); keps=(kb6,kb7)

  char* p = (char*)d_ws;
  auto take = [&](size_t bytes) -> void* {
    void* r = (void*)p;
    p += (bytes + 255) & ~(size_t)255;
    return r;
  };
  u16* P16       = (u16*)take(sizeof(u16) * (size_t)DBLK * N_NODES);     // 51.2 MB
  unsigned long long* ebuf = (unsigned long long*)take(sizeof(unsigned long long) * (size_t)N_EDGES); // 25.6 MB
  u16* X1b       = (u16*)take(sizeof(u16) * (size_t)N_NODES * HID);
  u16* h1b       = (u16*)take(sizeof(u16) * (size_t)N_NODES * HID);
  u16* XMLV      = (u16*)take(sizeof(u16) * (size_t)N_NODES * 32);
  u16* W1t       = (u16*)take(sizeof(u16) * (size_t)IN_DIM * HID);
  u16* Wt23      = (u16*)take(sizeof(u16) * 32 * HID);
  uint32_t* bofs_g = (uint32_t*)take(sizeof(uint32_t) * (size_t)DBLK * (NBKT + 1));
  int* tile_sum  = (int*)take(sizeof(int) * NTILE);
  float* out_is  = (float*)take(sizeof(float) * N_NODES);
  float* in_is   = (float*)take(sizeof(float) * N_NODES);
  int* row_ofs   = (int*)take(sizeof(int) * (N_NODES + 1));
  int* csr       = (int*)take(sizeof(int) * N_EDGES);
  float* bn      = (float*)take(sizeof(float) * 1024);

  hipMemsetAsync(bn, 0, sizeof(float) * 512, stream);

  hist_part_k<<<DBLK, 1024, 0, stream>>>(esrc, edst, P16, bofs_g, ebuf);
  degsum_k<<<NTILE, 256, 0, stream>>>(P16, out_is, in_is, row_ofs, tile_sum);
  fixup_k<<<NTILE, 256, 0, stream>>>(tile_sum, row_ofs);
  bplace_k<<<NBKT, 1024, 0, stream>>>(ebuf, bofs_g, row_ofs, csr);

  cast_w_k<<<(IN_DIM * HID + 32 * HID) / 256, 256, 0, stream>>>(W1, W2, W3, W1t, Wt23);

  gemm1_k<<<(N_NODES + G1_BM - 1) / G1_BM, 512, 0, stream>>>(x, out_is, kb[0], kb[1], W1t, X1b);
  agg_relu_k<<<N_NODES / 4, 256, 0, stream>>>(X1b, row_ofs, csr, in_is, h1b);
  bn_stats_k<<<256, 256, 0, stream>>>(h1b, bn);
  gemm23_k<<<(N_NODES + 63) / 64, 256, 0, stream>>>(h1b, Wt23, kb[2], kb[3], kb[4], kb[5],
                                                    out_is, bn, XMLV);
  agg_final_k<<<N_NODES / 4, 256, 0, stream>>>(XMLV, row_ofs, csr, in_is, kb[6], kb[7], out);
}

// Round 11
// 841.308 us; speedup vs baseline: 1.3270x; 1.0803x over previous
//
#include <hip/hip_runtime.h>
#include <stdint.h>

#define N_NODES 100000
#define N_EDGES 3200000
#define IN_DIM  512
#define HID     256
#define NCLS    16

// graph-prep geometry
#define DBLK   256                   // blocks (one per CU)
#define DCHUNK (N_EDGES / DBLK)      // 12500 edges per block
#define DWIN2  50000                 // nodes per LDS window in hist (byte counters, 100 KB)
#define NBKT   98                    // dst buckets of 1024 nodes  ((N_NODES+1023)>>10)
#define NTILE  ((N_NODES + 255) / 256)   // 391 scan tiles

typedef unsigned short u16;
typedef unsigned char u8;
typedef __attribute__((ext_vector_type(8))) short short8;
typedef __attribute__((ext_vector_type(4))) float float4v;

// ---------------- bf16 helpers ----------------
__device__ __forceinline__ float bf2f(u16 u) {
  return __uint_as_float(((uint32_t)u) << 16);
}
__device__ __forceinline__ u16 f2bf(float f) {   // round-to-nearest-even
  uint32_t u = __float_as_uint(f);
  return (u16)((u + 0x7fffu + ((u >> 16) & 1u)) >> 16);
}
__device__ __forceinline__ void acc8(float* a, uint4 v) {
  a[0] += bf2f((u16)(v.x & 0xffffu)); a[1] += bf2f((u16)(v.x >> 16));
  a[2] += bf2f((u16)(v.y & 0xffffu)); a[3] += bf2f((u16)(v.y >> 16));
  a[4] += bf2f((u16)(v.z & 0xffffu)); a[5] += bf2f((u16)(v.z >> 16));
  a[6] += bf2f((u16)(v.w & 0xffffu)); a[7] += bf2f((u16)(v.w >> 16));
}

// async global->LDS, 16B per lane: LDS dest = wave-uniform base + lane*16
__device__ __forceinline__ void gload16(const void* g, void* l) {
  __builtin_amdgcn_global_load_lds(
      (const __attribute__((address_space(1))) uint32_t*)g,
      (__attribute__((address_space(3))) uint32_t*)l, 16, 0, 0);
}

// ---------------- Threefry-2x32 (exact JAX schedule, partitionable mode) ----------------
__host__ __device__ __forceinline__ uint32_t rotl32(uint32_t v, int d) {
  return (v << d) | (v >> (32 - d));
}

__host__ __device__ __forceinline__ void threefry2x32(uint32_t k0, uint32_t k1,
    uint32_t x0, uint32_t x1, uint32_t& o0, uint32_t& o1) {
  uint32_t ks0 = k0, ks1 = k1, ks2 = k0 ^ k1 ^ 0x1BD11BDAu;
  x0 += ks0; x1 += ks1;
#define TF_R(r) { x0 += x1; x1 = rotl32(x1, r); x1 ^= x0; }
  TF_R(13) TF_R(15) TF_R(26) TF_R(6)
  x0 += ks1; x1 += ks2 + 1u;
  TF_R(17) TF_R(29) TF_R(16) TF_R(24)
  x0 += ks2; x1 += ks0 + 2u;
  TF_R(13) TF_R(15) TF_R(26) TF_R(6)
  x0 += ks0; x1 += ks1 + 3u;
  TF_R(17) TF_R(29) TF_R(16) TF_R(24)
  x0 += ks1; x1 += ks2 + 4u;
  TF_R(13) TF_R(15) TF_R(26) TF_R(6)
  x0 += ks2; x1 += ks0 + 5u;
#undef TF_R
  o0 = x0; o1 = x1;
}

__host__ __device__ __forceinline__ uint32_t tf_bits32(uint32_t k0, uint32_t k1, uint32_t idx) {
  uint32_t o0, o1;
  threefry2x32(k0, k1, 0u, idx, o0, o1);
  return o0 ^ o1;
}

// ---------------- erfinv: XLA/Giles f32 polynomial ----------------
__device__ __forceinline__ float erfinv_f32(float x) {
  float w = -log1pf(-x * x);
  float p;
  if (w < 5.0f) {
    w -= 2.5f;
    p = 2.81022636e-08f;
    p = fmaf(p, w, 3.43273939e-07f);
    p = fmaf(p, w, -3.5233877e-06f);
    p = fmaf(p, w, -4.39150654e-06f);
    p = fmaf(p, w, 0.00021858087f);
    p = fmaf(p, w, -0.00125372503f);
    p = fmaf(p, w, -0.00417768164f);
    p = fmaf(p, w, 0.246640727f);
    p = fmaf(p, w, 1.50140941f);
  } else {
    w = sqrtf(w) - 3.0f;
    p = -0.000200214257f;
    p = fmaf(p, w, 0.000100950558f);
    p = fmaf(p, w, 0.00134934322f);
    p = fmaf(p, w, -0.00367342844f);
    p = fmaf(p, w, 0.00573950773f);
    p = fmaf(p, w, -0.0076224613f);
    p = fmaf(p, w, 0.00943887047f);
    p = fmaf(p, w, 1.00167406f);
    p = fmaf(p, w, 2.83297682f);
  }
  return p * x;
}

// ---------------- hist+partition: privatized histogram + bucket-sort, one kernel ----------------
// P16[b][node] u16: lo8 = out-count, hi8 = in-count of block b's edge chunk.
// bofs_g[b][k]: exclusive prefix of block b's bucket-k edge count.
// Tail: bucket-partition this block's chunk into its private ebuf region
// (100 KB window, L2-resident writes; edge chunk re-read L2-warm).
__global__ __launch_bounds__(1024) void hist_part_k(
    const int* __restrict__ esrc, const int* __restrict__ edst,
    u16* __restrict__ P16, uint32_t* __restrict__ bofs_g,
    unsigned long long* __restrict__ ebuf) {
  __shared__ uint32_t h32[DWIN2 / 2];   // 25000 u32 = 100 KB, 2 nodes per word
  __shared__ uint32_t bcnt[NBKT + 1];
  const int b = blockIdx.x, tid = threadIdx.x;
  const int ebase = b * DCHUNK;
  if (tid < NBKT + 1) bcnt[tid] = 0u;
  for (int w = 0; w < 2; ++w) {
    const int lo = w * DWIN2;
    for (int i = tid; i < DWIN2 / 2; i += 1024) h32[i] = 0u;
    __syncthreads();
    for (int e = ebase + tid; e < ebase + DCHUNK; e += 1024) {
      int s = esrc[e], d = edst[e];
      unsigned su = (unsigned)(s - lo);
      if (su < (unsigned)DWIN2) atomicAdd(&h32[su >> 1], 1u << ((su & 1) * 16));
      unsigned du = (unsigned)(d - lo);
      if (du < (unsigned)DWIN2) atomicAdd(&h32[du >> 1], 0x100u << ((du & 1) * 16));
      if (w == 0) atomicAdd(&bcnt[d >> 10], 1u);
    }
    __syncthreads();
    for (int i = tid; i < DWIN2 / 2; i += 1024) {
      // word: [out_even | in_even<<8 | out_odd<<16 | in_odd<<24] == two P16 entries
      *(uint32_t*)(P16 + (size_t)b * N_NODES + lo + 2 * i) = h32[i];
    }
    __syncthreads();
  }
  if (tid == 0) {   // exclusive scan of 98 bucket counts
    uint32_t run = 0;
    for (int k = 0; k < NBKT; ++k) { uint32_t c = bcnt[k]; bcnt[k] = run; run += c; }
    bcnt[NBKT] = run;   // == DCHUNK
  }
  __syncthreads();
  if (tid < NBKT + 1) bofs_g[b * (NBKT + 1) + tid] = bcnt[tid];
  __syncthreads();
  // bucket partition (bcnt now serves as cursors); edge chunk is L2-warm
  for (int e = ebase + tid; e < ebase + DCHUNK; e += 1024) {
    int d = edst[e], s = esrc[e];
    uint32_t slot = atomicAdd(&bcnt[d >> 10], 1u);
    ebuf[(size_t)b * DCHUNK + slot] = ((unsigned long long)(uint32_t)s << 32) | (uint32_t)d;
  }
}

// ---------------- degsum: degrees + inv-sqrt + intra-tile exclusive scan of in-degree ----------------
__global__ void degsum_k(const u16* __restrict__ P16, float* __restrict__ out_is,
                         float* __restrict__ in_is, int* __restrict__ row_ofs,
                         int* __restrict__ tile_sum) {
  const int tid = threadIdx.x;
  const int n = blockIdx.x * 256 + tid;
  const int lane = tid & 63, wv = tid >> 6;
  uint32_t to = 0, ti = 0;
  if (n < N_NODES) {
#pragma unroll 8
    for (int b = 0; b < DBLK; ++b) {
      uint32_t v = P16[(size_t)b * N_NODES + n];
      to += v & 0xffu; ti += v >> 8;
    }
    out_is[n] = rsqrtf(fmaxf((float)to, 1.0f));
    in_is[n]  = rsqrtf(fmaxf((float)ti, 1.0f));
  }
  int sc = (int)ti;
#pragma unroll
  for (int d = 1; d < 64; d <<= 1) {
    int t = __shfl_up(sc, d, 64);
    if (lane >= d) sc += t;
  }
  __shared__ int ws[4];
  if (lane == 63) ws[wv] = sc;
  __syncthreads();
  int wbase = 0;
#pragma unroll
  for (int i = 0; i < 4; ++i) if (i < wv) wbase += ws[i];
  if (n < N_NODES) row_ofs[n] = wbase + sc - (int)ti;   // tile-local exclusive prefix
  if (tid == 0) tile_sum[blockIdx.x] = ws[0] + ws[1] + ws[2] + ws[3];
}

// ---------------- fixup: add tile bases (parallel over tiles) ----------------
__global__ void fixup_k(const int* __restrict__ tile_sum, int* __restrict__ row_ofs) {
  const int b = blockIdx.x, tid = threadIdx.x;
  const int lane = tid & 63, wv = tid >> 6;
  int v = 0;
  if (tid < b) v = tile_sum[tid];
  if (tid + 256 < b) v += tile_sum[tid + 256];
#pragma unroll
  for (int m = 1; m < 64; m <<= 1) v += __shfl_xor(v, m, 64);
  __shared__ int wr[4];
  if (lane == 0) wr[wv] = v;
  __syncthreads();
  const int base = wr[0] + wr[1] + wr[2] + wr[3];
  const int n = b * 256 + tid;
  if (n < N_NODES) row_ofs[n] += base;
  if (b == (int)gridDim.x - 1 && tid == 0) row_ofs[N_NODES] = base + tile_sum[b];
}

// ---------------- bplace: per-bucket scatter to final CSR slots (L2-local) ----------------
__global__ __launch_bounds__(1024) void bplace_k(
    const unsigned long long* __restrict__ ebuf, const uint32_t* __restrict__ bofs_g,
    const int* __restrict__ row_ofs, int* __restrict__ csr) {
  __shared__ uint32_t cur[1024];
  const int k = blockIdx.x, tid = threadIdx.x;
  const int lane = tid & 63, wv = tid >> 6;
  const int dbase = k << 10;
  int nd = N_NODES - dbase; if (nd > 1024) nd = 1024;
  if (tid < nd) cur[tid] = (uint32_t)row_ofs[dbase + tid];
  __syncthreads();
  for (int b = wv; b < DBLK; b += 16) {   // 16 waves; each owns 16 fragments
    uint32_t st = bofs_g[b * (NBKT + 1) + k];
    uint32_t en = bofs_g[b * (NBKT + 1) + k + 1];
    for (uint32_t i = st + lane; i < en; i += 64) {
      unsigned long long v = ebuf[(size_t)b * DCHUNK + i];
      int d = (int)(uint32_t)(v & 0xffffffffu);
      int s = (int)(uint32_t)(v >> 32);
      uint32_t slot = atomicAdd(&cur[d - dbase], 1u);
      csr[slot] = s;
    }
  }
}

// ---------------- W1t + Wt23 cast, single launch ----------------
__global__ void cast_w_k(const float* __restrict__ W1, const float* __restrict__ W2,
                         const float* __restrict__ W3, u16* __restrict__ W1t,
                         u16* __restrict__ Wt23) {
  int idx = blockIdx.x * blockDim.x + threadIdx.x;   // grid = (512*256 + 32*256)/256
  if (idx < IN_DIM * HID) {
    int k = idx >> 8, n = idx & 255;
    W1t[n * IN_DIM + k] = f2bf(W1[idx]);
  } else {
    int t = idx - IN_DIM * HID;
    int n = t >> 8, k = t & 255;
    float v = (n < 16) ? W2[k * NCLS + n] : W3[k * NCLS + (n - 16)];
    Wt23[n * HID + k] = f2bf(v);
  }
}

// ---------------- GEMM1 v3 (MFMA bf16): X1b = dropout1(x)*2*out_is @ W1, fused ----------------
#define G1_BM 128
#define G1_BKC 8   // chunks of 8 u16 (16 B) per row; BK = 64
__global__ __launch_bounds__(512, 2) void gemm1_k(
    const float* __restrict__ x, const float* __restrict__ out_is,
    uint32_t k0, uint32_t k1,
    const u16* __restrict__ W1t, u16* __restrict__ X1b) {
  __shared__ u16 As[G1_BM * 64];    // 16 KB, swizzled chunks
  __shared__ u16 Bs[256 * 64];      // 32 KB
  const int tid = threadIdx.x;
  const int wid = tid >> 6, lane = tid & 63;
  const int wr = wid >> 2, wc = wid & 3;     // wave tile: rows wr*64.., cols wc*64..
  const int m16 = lane & 15, q = lane >> 4;
  const int srow = lane >> 3, schunk = lane & 7;   // B staging: 8 rows x 8 chunks
  const long base_row = (long)blockIdx.x * G1_BM;

  const int arow_l = tid >> 2, acp = tid & 3;
  const long agrow = base_row + arow_l;
  const long asrow = (agrow < N_NODES) ? agrow : (N_NODES - 1);  // clamp (OOB rows unused)
  const float asc = 2.0f * out_is[asrow];
  const float* xrow = x + asrow * IN_DIM;
  const int aw0 = ((2 * acp)     ^ (arow_l & 7)) * 8;
  const int aw1 = ((2 * acp + 1) ^ (arow_l & 7)) * 8;

  float4v acc[4][4];
#pragma unroll
  for (int i = 0; i < 4; ++i)
#pragma unroll
    for (int j = 0; j < 4; ++j) acc[i][j] = (float4v)0.0f;

  for (int ks = 0; ks < IN_DIM / 64; ++ks) {
    const int kbase = ks * 64 + acp * 16;
    float4 f0 = *(const float4*)(xrow + kbase);
    float4 f1 = *(const float4*)(xrow + kbase + 4);
    float4 f2 = *(const float4*)(xrow + kbase + 8);
    float4 f3 = *(const float4*)(xrow + kbase + 12);
    float xv[16] = {f0.x, f0.y, f0.z, f0.w, f1.x, f1.y, f1.z, f1.w,
                    f2.x, f2.y, f2.z, f2.w, f3.x, f3.y, f3.z, f3.w};
    const uint32_t ibase = (uint32_t)asrow * IN_DIM + (uint32_t)kbase;
    u16 ob[16];
#pragma unroll
    for (int j = 0; j < 16; ++j) {
      uint32_t bits = tf_bits32(k0, k1, ibase + (uint32_t)j);
      ob[j] = f2bf((bits >> 31) ? 0.0f : xv[j] * asc);
    }
    uint4 pka, pkb;
    pka.x = (uint32_t)ob[0] | ((uint32_t)ob[1] << 16);
    pka.y = (uint32_t)ob[2] | ((uint32_t)ob[3] << 16);
    pka.z = (uint32_t)ob[4] | ((uint32_t)ob[5] << 16);
    pka.w = (uint32_t)ob[6] | ((uint32_t)ob[7] << 16);
    pkb.x = (uint32_t)ob[8] | ((uint32_t)ob[9] << 16);
    pkb.y = (uint32_t)ob[10] | ((uint32_t)ob[11] << 16);
    pkb.z = (uint32_t)ob[12] | ((uint32_t)ob[13] << 16);
    pkb.w = (uint32_t)ob[14] | ((uint32_t)ob[15] << 16);
    *(uint4*)(As + arow_l * 64 + aw0) = pka;
    *(uint4*)(As + arow_l * 64 + aw1) = pkb;
#pragma unroll
    for (int i = 0; i < 4; ++i) {
      int j = wid * 4 + i;
      int n = j * 8 + srow;
      int gch = ks * G1_BKC + (schunk ^ (n & 7));
      gload16(W1t + (size_t)n * IN_DIM + gch * 8, Bs + j * 512);
    }
    __syncthreads();
#pragma unroll
    for (int kk = 0; kk < 2; ++kk) {
      short8 a[4], b[4];
      const int kq = kk * 4 + q;
      const int c = kq ^ (m16 & 7);
#pragma unroll
      for (int rt = 0; rt < 4; ++rt) {
        int row = wr * 64 + rt * 16 + m16;
        a[rt] = *(const short8*)(As + row * 64 + c * 8);
      }
#pragma unroll
      for (int ct = 0; ct < 4; ++ct) {
        int n = wc * 64 + ct * 16 + m16;
        b[ct] = *(const short8*)(Bs + n * 64 + c * 8);
      }
#pragma unroll
      for (int rt = 0; rt < 4; ++rt)
#pragma unroll
        for (int ct = 0; ct < 4; ++ct)
          acc[rt][ct] = __builtin_amdgcn_mfma_f32_16x16x32_bf16(a[rt], b[ct], acc[rt][ct], 0, 0, 0);
    }
    __syncthreads();
  }
#pragma unroll
  for (int rt = 0; rt < 4; ++rt) {
#pragma unroll
    for (int r = 0; r < 4; ++r) {
      long grow = base_row + wr * 64 + rt * 16 + q * 4 + r;
      if (grow < N_NODES) {
#pragma unroll
        for (int ct = 0; ct < 4; ++ct)
          X1b[grow * HID + wc * 64 + ct * 16 + m16] = f2bf(acc[rt][ct][r]);
      }
    }
  }
}

// ---------------- CSR gather-sum (bf16) + relu -> h1 bf16  +  fused mask-gen ----------------
// Fabric-bound gather (VALU ~29% busy): the tail generates the two hidden-dropout
// bit-masks in otherwise-idle VALU slots. 6.4M threads; first 3.2M produce mask-a
// bytes, last 3.2M produce mask-b bytes (8 threefry calls each; 51.2M total).
__global__ __launch_bounds__(256) void agg_relu_k(
    const u16* __restrict__ X1b, const int* __restrict__ row_ofs,
    const int* __restrict__ csr, const float* __restrict__ in_is,
    uint32_t ka0, uint32_t ka1, uint32_t kb0, uint32_t kb1,
    u8* __restrict__ mska, u8* __restrict__ mskb,
    u16* __restrict__ h1b) {
  int d = blockIdx.x * 4 + (threadIdx.x >> 6);  // exact: 25000*4 = N
  int lane = threadIdx.x & 63;
  int half = lane >> 5;
  int col = (lane & 31) * 8;
  int beg = row_ofs[d], end = row_ofs[d + 1];
  float a[8];
#pragma unroll
  for (int i = 0; i < 8; ++i) a[i] = 0.0f;
  int j = beg + half;
  for (; j + 14 < end; j += 16) {
    int s0 = csr[j],      s1 = csr[j + 2],  s2 = csr[j + 4],  s3 = csr[j + 6];
    int s4 = csr[j + 8],  s5 = csr[j + 10], s6 = csr[j + 12], s7 = csr[j + 14];
    uint4 v0 = *(const uint4*)(X1b + (size_t)s0 * HID + col);
    uint4 v1 = *(const uint4*)(X1b + (size_t)s1 * HID + col);
    uint4 v2 = *(const uint4*)(X1b + (size_t)s2 * HID + col);
    uint4 v3 = *(const uint4*)(X1b + (size_t)s3 * HID + col);
    uint4 v4 = *(const uint4*)(X1b + (size_t)s4 * HID + col);
    uint4 v5 = *(const uint4*)(X1b + (size_t)s5 * HID + col);
    uint4 v6 = *(const uint4*)(X1b + (size_t)s6 * HID + col);
    uint4 v7 = *(const uint4*)(X1b + (size_t)s7 * HID + col);
    acc8(a, v0); acc8(a, v1); acc8(a, v2); acc8(a, v3);
    acc8(a, v4); acc8(a, v5); acc8(a, v6); acc8(a, v7);
  }
  for (; j + 6 < end; j += 8) {
    int s0 = csr[j], s1 = csr[j + 2], s2 = csr[j + 4], s3 = csr[j + 6];
    uint4 v0 = *(const uint4*)(X1b + (size_t)s0 * HID + col);
    uint4 v1 = *(const uint4*)(X1b + (size_t)s1 * HID + col);
    uint4 v2 = *(const uint4*)(X1b + (size_t)s2 * HID + col);
    uint4 v3 = *(const uint4*)(X1b + (size_t)s3 * HID + col);
    acc8(a, v0); acc8(a, v1); acc8(a, v2); acc8(a, v3);
  }
  for (; j < end; j += 2) {
    uint4 v0 = *(const uint4*)(X1b + (size_t)csr[j] * HID + col);
    acc8(a, v0);
  }
#pragma unroll
  for (int i = 0; i < 8; ++i) a[i] += __shfl(a[i], lane ^ 32, 64);
  if (half == 0) {
    float is = in_is[d];
    u16 o[8];
#pragma unroll
    for (int i = 0; i < 8; ++i) o[i] = f2bf(fmaxf(a[i] * is, 0.0f));
    uint4 pk;
    pk.x = (uint32_t)o[0] | ((uint32_t)o[1] << 16);
    pk.y = (uint32_t)o[2] | ((uint32_t)o[3] << 16);
    pk.z = (uint32_t)o[4] | ((uint32_t)o[5] << 16);
    pk.w = (uint32_t)o[6] | ((uint32_t)o[7] << 16);
    *(uint4*)(h1b + (size_t)d * HID + col) = pk;
  }
  // ---- fused hidden-dropout mask generation (fills idle VALU; bit set = keep) ----
  {
    const uint32_t NB = (uint32_t)N_NODES * HID / 8;   // 3.2M bytes per mask
    uint32_t gid = blockIdx.x * 256u + threadIdx.x;    // 6.4M threads total
    const bool isB = gid >= NB;
    const uint32_t mi = isB ? gid - NB : gid;          // mask byte index
    const uint32_t kk0 = isB ? kb0 : ka0, kk1 = isB ? kb1 : ka1;
    const uint32_t ib = mi * 8u;                       // element index base
    uint32_t bits = 0u;
#pragma unroll
    for (uint32_t jj = 0; jj < 8; ++jj)
      bits |= ((~tf_bits32(kk0, kk1, ib + jj)) >> 31) << jj;
    (isB ? mskb : mska)[mi] = (u8)bits;
  }
}

// ---------------- BatchNorm stats (bf16 in, fp32 accumulate), vectorized ----------------
__global__ __launch_bounds__(256) void bn_stats_k(const u16* __restrict__ h1b,
                                                  float* __restrict__ bn) {
  __shared__ float ls[512];
  const int tid = threadIdx.x;
  const int cb = (tid & 31) * 8;   // col base
  const int ms = tid >> 5;         // row-stream 0..7
  float s[8], s2[8];
#pragma unroll
  for (int i = 0; i < 8; ++i) { s[i] = 0.f; s2[i] = 0.f; }
  for (int m = ms;; m += 8) {
    int r = blockIdx.x + 256 * m;
    if (r >= N_NODES) break;
    uint4 v = *(const uint4*)(h1b + (size_t)r * HID + cb);
    float f[8];
    f[0] = bf2f((u16)(v.x & 0xffffu)); f[1] = bf2f((u16)(v.x >> 16));
    f[2] = bf2f((u16)(v.y & 0xffffu)); f[3] = bf2f((u16)(v.y >> 16));
    f[4] = bf2f((u16)(v.z & 0xffffu)); f[5] = bf2f((u16)(v.z >> 16));
    f[6] = bf2f((u16)(v.w & 0xffffu)); f[7] = bf2f((u16)(v.w >> 16));
#pragma unroll
    for (int i = 0; i < 8; ++i) { s[i] += f[i]; s2[i] += f[i] * f[i]; }
  }
  ls[tid] = 0.f; ls[tid + 256] = 0.f;
  __syncthreads();
#pragma unroll
  for (int i = 0; i < 8; ++i) {
    atomicAdd(&ls[cb + i], s[i]);
    atomicAdd(&ls[256 + cb + i], s2[i]);
  }
  __syncthreads();
  atomicAdd(&bn[tid], ls[tid]);
  atomicAdd(&bn[HID + tid], ls[256 + tid]);
}

// ---------------- GEMM2/3 (MFMA): reads bit-packed masks + bn finalize ----------------
#define WLS 264   // u16 row stride for Wls: dword-stride 132 -> 2-way bank alias (free)
__global__ __launch_bounds__(256) void gemm23_k(
    const u16* __restrict__ h1b, const u16* __restrict__ Wt23,
    const u8* __restrict__ mska, const u8* __restrict__ mskb,
    const float* __restrict__ out_is, const float* __restrict__ bn,
    u16* __restrict__ XMLV) {
  __shared__ u16 Wls[32 * WLS];
  __shared__ float cB[HID], cA[HID];
  const int tid = threadIdx.x;
#pragma unroll
  for (int i = 0; i < 4; ++i) {   // stage Wt23 (16KB) into padded LDS
    int idx = tid + i * 256;      // 1024 uint4 chunks
    int n = idx >> 5, c = idx & 31;
    *(uint4*)(Wls + n * WLS + c * 8) = ((const uint4*)Wt23)[idx];
  }
  {  // bn finalize: cB = istd, cA = -mean*istd
    float mean = bn[tid] * (1.0f / (float)N_NODES);
    float var = bn[HID + tid] * (1.0f / (float)N_NODES) - mean * mean;
    float istd = rsqrtf(var + 1e-5f);
    cB[tid] = istd;
    cA[tid] = -mean * istd;
  }
  __syncthreads();

  const int wv = tid >> 6, lane = tid & 63;
  const int m = lane & 15, q = lane >> 4;
  const long arow = (long)blockIdx.x * 64 + wv * 16 + m;   // A row this lane loads
  const bool valid = arow < N_NODES;
  const float osc = valid ? 2.0f * out_is[arow] : 0.0f;

  float4v accM = (float4v)0.0f, accL = (float4v)0.0f;
  for (int kc = 0; kc < HID; kc += 32) {
    const int kof = kc + q * 8;
    uint4 hv = make_uint4(0, 0, 0, 0);
    uint32_t wa = 0, wb = 0;
    if (valid) {
      hv = *(const uint4*)(h1b + arow * HID + kof);
      uint32_t bofs = ((uint32_t)arow * HID + (uint32_t)kc) >> 3;  // byte ofs, 4-aligned
      wa = (*(const uint32_t*)(mska + bofs)) >> (q * 8);
      wb = (*(const uint32_t*)(mskb + bofs)) >> (q * 8);
    }
    float4 B0 = *(const float4*)(cB + kof);
    float4 B1 = *(const float4*)(cB + kof + 4);
    float4 A0 = *(const float4*)(cA + kof);
    float4 A1 = *(const float4*)(cA + kof + 4);
    float hval[8] = {
      bf2f((u16)(hv.x & 0xffffu)), bf2f((u16)(hv.x >> 16)),
      bf2f((u16)(hv.y & 0xffffu)), bf2f((u16)(hv.y >> 16)),
      bf2f((u16)(hv.z & 0xffffu)), bf2f((u16)(hv.z >> 16)),
      bf2f((u16)(hv.w & 0xffffu)), bf2f((u16)(hv.w >> 16))};
    float nb[8] = {B0.x, B0.y, B0.z, B0.w, B1.x, B1.y, B1.z, B1.w};
    float na[8] = {A0.x, A0.y, A0.z, A0.w, A1.x, A1.y, A1.z, A1.w};
    short8 Aa, Ab;
#pragma unroll
    for (int jj = 0; jj < 8; ++jj) {
      float t = fmaf(hval[jj], nb[jj], na[jj]) * osc;
      u16 tb = f2bf(t);
      Aa[jj] = (short)(((wa >> jj) & 1u) ? tb : 0);
      Ab[jj] = (short)(((wb >> jj) & 1u) ? tb : 0);
    }
    short8 Bm = *(const short8*)(Wls + m * WLS + kof);          // W2 col m
    short8 Bl = *(const short8*)(Wls + (16 + m) * WLS + kof);   // W3 col m
    accM = __builtin_amdgcn_mfma_f32_16x16x32_bf16(Aa, Bm, accM, 0, 0, 0);
    accL = __builtin_amdgcn_mfma_f32_16x16x32_bf16(Ab, Bl, accL, 0, 0, 0);
  }
#pragma unroll
  for (int r = 0; r < 4; ++r) {
    long srow = (long)blockIdx.x * 64 + wv * 16 + q * 4 + r;
    if (srow < N_NODES) {
      XMLV[srow * 32 + m]      = f2bf(accM[r]);
      XMLV[srow * 32 + 16 + m] = f2bf(accL[r]);
    }
  }
}

// ---------------- final: aggregate interleaved mu|logvar + reparameterize ----------------
__global__ __launch_bounds__(256) void agg_final_k(
    const u16* __restrict__ XMLV, const int* __restrict__ row_ofs,
    const int* __restrict__ csr, const float* __restrict__ in_is,
    uint32_t ke0, uint32_t ke1, float* __restrict__ out) {
  int g = blockIdx.x * 4 + (threadIdx.x >> 6);  // exact: 25000*4 = N
  int lane = threadIdx.x & 63;
  int half = lane >> 5, c = lane & 31;
  int beg = row_ofs[g], end = row_ofs[g + 1];
  float s = 0.f;
  int j = beg + half;
  for (; j + 14 < end; j += 16) {
    int s0 = csr[j],      s1 = csr[j + 2],  s2 = csr[j + 4],  s3 = csr[j + 6];
    int s4 = csr[j + 8],  s5 = csr[j + 10], s6 = csr[j + 12], s7 = csr[j + 14];
    float v0 = bf2f(XMLV[(size_t)s0 * 32 + c]);
    float v1 = bf2f(XMLV[(size_t)s1 * 32 + c]);
    float v2 = bf2f(XMLV[(size_t)s2 * 32 + c]);
    float v3 = bf2f(XMLV[(size_t)s3 * 32 + c]);
    float v4 = bf2f(XMLV[(size_t)s4 * 32 + c]);
    float v5 = bf2f(XMLV[(size_t)s5 * 32 + c]);
    float v6 = bf2f(XMLV[(size_t)s6 * 32 + c]);
    float v7 = bf2f(XMLV[(size_t)s7 * 32 + c]);
    s += v0; s += v1; s += v2; s += v3;
    s += v4; s += v5; s += v6; s += v7;
  }
#pragma unroll
  for (int k = 0; k < 8; ++k) {
    int e = j + 2 * k;
    if (e < end) s += bf2f(XMLV[(size_t)csr[e] * 32 + c]);
  }
  s += __shfl(s, lane ^ 32, 64);
  if (half == 0) {
    s *= in_is[g];
    float other = __shfl(s, lane ^ 16, 64);  // mu lane c gets logvar from lane c+16
    if (c < 16) {
      uint32_t i = (uint32_t)(g * NCLS + c);
      uint32_t bits = tf_bits32(ke0, ke1, i);
      float f = __uint_as_float((bits >> 9) | 0x3f800000u) - 1.0f;
      const float lo = -0.99999994f;          // nextafter(-1,0)
      float u = fmaxf(lo, fmaf(f, 2.0f, lo)); // (hi-lo) rounds to exactly 2.0f
      float eps = 1.41421356f * erfinv_f32(u);
      out[i] = eps * expf(other) + s;
    }
  }
}

// ---------------- host ----------------
extern "C" void kernel_launch(void* const* d_in, const int* in_sizes, int n_in,
                              void* d_out, int out_size, void* d_ws, size_t ws_size,
                              hipStream_t stream) {
  (void)in_sizes; (void)n_in; (void)out_size; (void)ws_size;
  const float* x  = (const float*)d_in[0];
  const float* W1 = (const float*)d_in[1];
  const float* W2 = (const float*)d_in[2];
  const float* W3 = (const float*)d_in[3];
  const int* esrc = (const int*)d_in[4];
  const int* edst = (const int*)d_in[5];
  float* out = (float*)d_out;

  uint32_t kb[8];
  for (int j = 0; j < 4; ++j)
    threefry2x32(0u, 42u, 0u, (uint32_t)j, kb[2 * j], kb[2 * j + 1]);
  // k1=(kb0,kb1) drop-x; k2a=(kb2,kb3); k2b=(kb4,kb5); keps=(kb6,kb7)

  char* p = (char*)d_ws;
  auto take = [&](size_t bytes) -> void* {
    void* r = (void*)p;
    p += (bytes + 255) & ~(size_t)255;
    return r;
  };
  u16* P16       = (u16*)take(sizeof(u16) * (size_t)DBLK * N_NODES);     // 51.2 MB
  unsigned long long* ebuf = (unsigned long long*)take(sizeof(unsigned long long) * (size_t)N_EDGES); // 25.6 MB
  u16* X1b       = (u16*)take(sizeof(u16) * (size_t)N_NODES * HID);
  u16* h1b       = (u16*)take(sizeof(u16) * (size_t)N_NODES * HID);
  u16* XMLV      = (u16*)take(sizeof(u16) * (size_t)N_NODES * 32);
  u16* W1t       = (u16*)take(sizeof(u16) * (size_t)IN_DIM * HID);
  u16* Wt23      = (u16*)take(sizeof(u16) * 32 * HID);
  u8* mska       = (u8*)take((size_t)N_NODES * HID / 8);                 // 3.2 MB
  u8* mskb       = (u8*)take((size_t)N_NODES * HID / 8);
  uint32_t* bofs_g = (uint32_t*)take(sizeof(uint32_t) * (size_t)DBLK * (NBKT + 1));
  int* tile_sum  = (int*)take(sizeof(int) * NTILE);
  float* out_is  = (float*)take(sizeof(float) * N_NODES);
  float* in_is   = (float*)take(sizeof(float) * N_NODES);
  int* row_ofs   = (int*)take(sizeof(int) * (N_NODES + 1));
  int* csr       = (int*)take(sizeof(int) * N_EDGES);
  float* bn      = (float*)take(sizeof(float) * 1024);

  hipMemsetAsync(bn, 0, sizeof(float) * 512, stream);

  hist_part_k<<<DBLK, 1024, 0, stream>>>(esrc, edst, P16, bofs_g, ebuf);
  degsum_k<<<NTILE, 256, 0, stream>>>(P16, out_is, in_is, row_ofs, tile_sum);
  fixup_k<<<NTILE, 256, 0, stream>>>(tile_sum, row_ofs);
  bplace_k<<<NBKT, 1024, 0, stream>>>(ebuf, bofs_g, row_ofs, csr);

  cast_w_k<<<(IN_DIM * HID + 32 * HID) / 256, 256, 0, stream>>>(W1, W2, W3, W1t, Wt23);

  gemm1_k<<<(N_NODES + G1_BM - 1) / G1_BM, 512, 0, stream>>>(x, out_is, kb[0], kb[1], W1t, X1b);
  agg_relu_k<<<N_NODES / 4, 256, 0, stream>>>(X1b, row_ofs, csr, in_is,
                                              kb[2], kb[3], kb[4], kb[5], mska, mskb, h1b);
  bn_stats_k<<<256, 256, 0, stream>>>(h1b, bn);
  gemm23_k<<<(N_NODES + 63) / 64, 256, 0, stream>>>(h1b, Wt23, mska, mskb, out_is, bn, XMLV);
  agg_final_k<<<N_NODES / 4, 256, 0, stream>>>(XMLV, row_ofs, csr, in_is, kb[6], kb[7], out);
}

// Round 12
// 828.361 us; speedup vs baseline: 1.3477x; 1.0156x over previous
//
#include <hip/hip_runtime.h>
#include <stdint.h>

#define N_NODES 100000
#define N_EDGES 3200000
#define IN_DIM  512
#define HID     256
#define NCLS    16

// graph-prep geometry
#define DBLK   256                   // blocks (one per CU)
#define DCHUNK (N_EDGES / DBLK)      // 12500 edges per block
#define NBKT   98                    // dst buckets of 1024 nodes  ((N_NODES+1023)>>10)
#define NREP   8                     // replicated bucket counters
#define NTILE  ((N_NODES + 255) / 256)   // 391 scan tiles

typedef unsigned short u16;
typedef unsigned char u8;
typedef __attribute__((ext_vector_type(8))) short short8;
typedef __attribute__((ext_vector_type(4))) float float4v;

// ---------------- bf16 helpers ----------------
__device__ __forceinline__ float bf2f(u16 u) {
  return __uint_as_float(((uint32_t)u) << 16);
}
__device__ __forceinline__ u16 f2bf(float f) {   // round-to-nearest-even
  uint32_t u = __float_as_uint(f);
  return (u16)((u + 0x7fffu + ((u >> 16) & 1u)) >> 16);
}
__device__ __forceinline__ void acc8(float* a, uint4 v) {
  a[0] += bf2f((u16)(v.x & 0xffffu)); a[1] += bf2f((u16)(v.x >> 16));
  a[2] += bf2f((u16)(v.y & 0xffffu)); a[3] += bf2f((u16)(v.y >> 16));
  a[4] += bf2f((u16)(v.z & 0xffffu)); a[5] += bf2f((u16)(v.z >> 16));
  a[6] += bf2f((u16)(v.w & 0xffffu)); a[7] += bf2f((u16)(v.w >> 16));
}

// async global->LDS, 16B per lane: LDS dest = wave-uniform base + lane*16
__device__ __forceinline__ void gload16(const void* g, void* l) {
  __builtin_amdgcn_global_load_lds(
      (const __attribute__((address_space(1))) uint32_t*)g,
      (__attribute__((address_space(3))) uint32_t*)l, 16, 0, 0);
}

// ---------------- Threefry-2x32 (exact JAX schedule, partitionable mode) ----------------
__host__ __device__ __forceinline__ uint32_t rotl32(uint32_t v, int d) {
  return (v << d) | (v >> (32 - d));
}

__host__ __device__ __forceinline__ void threefry2x32(uint32_t k0, uint32_t k1,
    uint32_t x0, uint32_t x1, uint32_t& o0, uint32_t& o1) {
  uint32_t ks0 = k0, ks1 = k1, ks2 = k0 ^ k1 ^ 0x1BD11BDAu;
  x0 += ks0; x1 += ks1;
#define TF_R(r) { x0 += x1; x1 = rotl32(x1, r); x1 ^= x0; }
  TF_R(13) TF_R(15) TF_R(26) TF_R(6)
  x0 += ks1; x1 += ks2 + 1u;
  TF_R(17) TF_R(29) TF_R(16) TF_R(24)
  x0 += ks2; x1 += ks0 + 2u;
  TF_R(13) TF_R(15) TF_R(26) TF_R(6)
  x0 += ks0; x1 += ks1 + 3u;
  TF_R(17) TF_R(29) TF_R(16) TF_R(24)
  x0 += ks1; x1 += ks2 + 4u;
  TF_R(13) TF_R(15) TF_R(26) TF_R(6)
  x0 += ks2; x1 += ks0 + 5u;
#undef TF_R
  o0 = x0; o1 = x1;
}

__host__ __device__ __forceinline__ uint32_t tf_bits32(uint32_t k0, uint32_t k1, uint32_t idx) {
  uint32_t o0, o1;
  threefry2x32(k0, k1, 0u, idx, o0, o1);
  return o0 ^ o1;
}

// ---------------- erfinv: XLA/Giles f32 polynomial ----------------
__device__ __forceinline__ float erfinv_f32(float x) {
  float w = -log1pf(-x * x);
  float p;
  if (w < 5.0f) {
    w -= 2.5f;
    p = 2.81022636e-08f;
    p = fmaf(p, w, 3.43273939e-07f);
    p = fmaf(p, w, -3.5233877e-06f);
    p = fmaf(p, w, -4.39150654e-06f);
    p = fmaf(p, w, 0.00021858087f);
    p = fmaf(p, w, -0.00125372503f);
    p = fmaf(p, w, -0.00417768164f);
    p = fmaf(p, w, 0.246640727f);
    p = fmaf(p, w, 1.50140941f);
  } else {
    w = sqrtf(w) - 3.0f;
    p = -0.000200214257f;
    p = fmaf(p, w, 0.000100950558f);
    p = fmaf(p, w, 0.00134934322f);
    p = fmaf(p, w, -0.00367342844f);
    p = fmaf(p, w, 0.00573950773f);
    p = fmaf(p, w, -0.0076224613f);
    p = fmaf(p, w, 0.00943887047f);
    p = fmaf(p, w, 1.00167406f);
    p = fmaf(p, w, 2.83297682f);
  }
  return p * x;
}

// ---------------- hist+partition: nibble histogram (1 window) + bucket-sort ----------------
// P8[b][node] u8: lo4 = out-count, hi4 = in-count of block b's edge chunk
// (per-(block,node) counts are Poisson(0.125); max ~7 < 16, no nibble carry).
// bofs_g[b][k]: exclusive prefix of block b's bucket-k edge count.
// ebuf u32: s<<10 | (d&1023)  (s < 2^17; d's bucket is implicit from slot).
__global__ __launch_bounds__(1024) void hist_part_k(
    const int* __restrict__ esrc, const int* __restrict__ edst,
    u8* __restrict__ P8, uint32_t* __restrict__ bofs_g,
    uint32_t* __restrict__ ebuf) {
  __shared__ uint32_t h32[N_NODES / 4];       // 25000 u32 = 100 KB: 4 nodes/word
  __shared__ uint32_t brep[NBKT * NREP];      // replicated bucket counters
  __shared__ uint32_t bcnt[NBKT + 1];
  const int b = blockIdx.x, tid = threadIdx.x;
  const int ebase = b * DCHUNK;
  for (int i = tid; i < N_NODES / 4; i += 1024) h32[i] = 0u;
  if (tid < NBKT * NREP) brep[tid] = 0u;
  __syncthreads();
  const int rep = tid & (NREP - 1);
  for (int e = ebase + tid; e < ebase + DCHUNK; e += 1024) {
    int s = esrc[e], d = edst[e];
    atomicAdd(&h32[s >> 2], 1u << ((s & 3) * 8));        // out-count, lo nibble
    atomicAdd(&h32[d >> 2], 16u << ((d & 3) * 8));       // in-count, hi nibble
    atomicAdd(&brep[(d >> 10) * NREP + rep], 1u);
  }
  __syncthreads();
  for (int i = tid; i < N_NODES / 4; i += 1024)
    *(uint32_t*)(P8 + (size_t)b * N_NODES + 4 * i) = h32[i];
  if (tid < NBKT) {
    uint32_t c = 0;
#pragma unroll
    for (int r = 0; r < NREP; ++r) c += brep[tid * NREP + r];
    bcnt[tid] = c;
  }
  __syncthreads();
  if (tid == 0) {   // exclusive scan of 98 bucket counts
    uint32_t run = 0;
    for (int k = 0; k < NBKT; ++k) { uint32_t c = bcnt[k]; bcnt[k] = run; run += c; }
    bcnt[NBKT] = run;   // == DCHUNK
  }
  __syncthreads();
  if (tid < NBKT + 1) bofs_g[b * (NBKT + 1) + tid] = bcnt[tid];
  __syncthreads();
  // bucket partition (bcnt now serves as cursors); edge chunk is L2-warm
  for (int e = ebase + tid; e < ebase + DCHUNK; e += 1024) {
    int d = edst[e], s = esrc[e];
    uint32_t slot = atomicAdd(&bcnt[d >> 10], 1u);
    ebuf[(size_t)b * DCHUNK + slot] = ((uint32_t)s << 10) | ((uint32_t)d & 1023u);
  }
}

// ---------------- degsum: degrees + inv-sqrt + intra-tile exclusive scan of in-degree ----------------
__global__ void degsum_k(const u8* __restrict__ P8, float* __restrict__ out_is,
                         float* __restrict__ in_is, int* __restrict__ row_ofs,
                         int* __restrict__ tile_sum) {
  const int tid = threadIdx.x;
  const int n = blockIdx.x * 256 + tid;
  const int lane = tid & 63, wv = tid >> 6;
  uint32_t to = 0, ti = 0;
  if (n < N_NODES) {
#pragma unroll 8
    for (int b = 0; b < DBLK; ++b) {
      uint32_t v = P8[(size_t)b * N_NODES + n];
      to += v & 0xfu; ti += v >> 4;
    }
    out_is[n] = rsqrtf(fmaxf((float)to, 1.0f));
    in_is[n]  = rsqrtf(fmaxf((float)ti, 1.0f));
  }
  int sc = (int)ti;
#pragma unroll
  for (int d = 1; d < 64; d <<= 1) {
    int t = __shfl_up(sc, d, 64);
    if (lane >= d) sc += t;
  }
  __shared__ int ws[4];
  if (lane == 63) ws[wv] = sc;
  __syncthreads();
  int wbase = 0;
#pragma unroll
  for (int i = 0; i < 4; ++i) if (i < wv) wbase += ws[i];
  if (n < N_NODES) row_ofs[n] = wbase + sc - (int)ti;   // tile-local exclusive prefix
  if (tid == 0) tile_sum[blockIdx.x] = ws[0] + ws[1] + ws[2] + ws[3];
}

// ---------------- fixup: add tile bases (parallel over tiles) ----------------
__global__ void fixup_k(const int* __restrict__ tile_sum, int* __restrict__ row_ofs) {
  const int b = blockIdx.x, tid = threadIdx.x;
  const int lane = tid & 63, wv = tid >> 6;
  int v = 0;
  if (tid < b) v = tile_sum[tid];
  if (tid + 256 < b) v += tile_sum[tid + 256];
#pragma unroll
  for (int m = 1; m < 64; m <<= 1) v += __shfl_xor(v, m, 64);
  __shared__ int wr[4];
  if (lane == 0) wr[wv] = v;
  __syncthreads();
  const int base = wr[0] + wr[1] + wr[2] + wr[3];
  const int n = b * 256 + tid;
  if (n < N_NODES) row_ofs[n] += base;
  if (b == (int)gridDim.x - 1 && tid == 0) row_ofs[N_NODES] = base + tile_sum[b];
}

// ---------------- bplace: per-bucket scatter to final CSR slots (L2-local) ----------------
__global__ __launch_bounds__(1024) void bplace_k(
    const uint32_t* __restrict__ ebuf, const uint32_t* __restrict__ bofs_g,
    const int* __restrict__ row_ofs, int* __restrict__ csr) {
  __shared__ uint32_t cur[1024];
  const int k = blockIdx.x, tid = threadIdx.x;
  const int lane = tid & 63, wv = tid >> 6;
  const int dbase = k << 10;
  int nd = N_NODES - dbase; if (nd > 1024) nd = 1024;
  if (tid < nd) cur[tid] = (uint32_t)row_ofs[dbase + tid];
  __syncthreads();
  for (int b = wv; b < DBLK; b += 16) {   // 16 waves; each owns 16 fragments
    uint32_t st = bofs_g[b * (NBKT + 1) + k];
    uint32_t en = bofs_g[b * (NBKT + 1) + k + 1];
    for (uint32_t i = st + lane; i < en; i += 64) {
      uint32_t v = ebuf[(size_t)b * DCHUNK + i];
      int dl = (int)(v & 1023u);        // d - dbase
      int s = (int)(v >> 10);
      uint32_t slot = atomicAdd(&cur[dl], 1u);
      csr[slot] = s;
    }
  }
}

// ---------------- W1t + Wt23 cast, single launch ----------------
__global__ void cast_w_k(const float* __restrict__ W1, const float* __restrict__ W2,
                         const float* __restrict__ W3, u16* __restrict__ W1t,
                         u16* __restrict__ Wt23) {
  int idx = blockIdx.x * blockDim.x + threadIdx.x;   // grid = (512*256 + 32*256)/256
  if (idx < IN_DIM * HID) {
    int k = idx >> 8, n = idx & 255;
    W1t[n * IN_DIM + k] = f2bf(W1[idx]);
  } else {
    int t = idx - IN_DIM * HID;
    int n = t >> 8, k = t & 255;
    float v = (n < 16) ? W2[k * NCLS + n] : W3[k * NCLS + (n - 16)];
    Wt23[n * HID + k] = f2bf(v);
  }
}

// ---------------- GEMM1 v3 (MFMA bf16): X1b = dropout1(x)*2*out_is @ W1, fused ----------------
#define G1_BM 128
#define G1_BKC 8   // chunks of 8 u16 (16 B) per row; BK = 64
__global__ __launch_bounds__(512, 2) void gemm1_k(
    const float* __restrict__ x, const float* __restrict__ out_is,
    uint32_t k0, uint32_t k1,
    const u16* __restrict__ W1t, u16* __restrict__ X1b) {
  __shared__ u16 As[G1_BM * 64];    // 16 KB, swizzled chunks
  __shared__ u16 Bs[256 * 64];      // 32 KB
  const int tid = threadIdx.x;
  const int wid = tid >> 6, lane = tid & 63;
  const int wr = wid >> 2, wc = wid & 3;     // wave tile: rows wr*64.., cols wc*64..
  const int m16 = lane & 15, q = lane >> 4;
  const int srow = lane >> 3, schunk = lane & 7;   // B staging: 8 rows x 8 chunks
  const long base_row = (long)blockIdx.x * G1_BM;

  const int arow_l = tid >> 2, acp = tid & 3;
  const long agrow = base_row + arow_l;
  const long asrow = (agrow < N_NODES) ? agrow : (N_NODES - 1);  // clamp (OOB rows unused)
  const float asc = 2.0f * out_is[asrow];
  const float* xrow = x + asrow * IN_DIM;
  const int aw0 = ((2 * acp)     ^ (arow_l & 7)) * 8;
  const int aw1 = ((2 * acp + 1) ^ (arow_l & 7)) * 8;

  float4v acc[4][4];
#pragma unroll
  for (int i = 0; i < 4; ++i)
#pragma unroll
    for (int j = 0; j < 4; ++j) acc[i][j] = (float4v)0.0f;

  for (int ks = 0; ks < IN_DIM / 64; ++ks) {
    const int kbase = ks * 64 + acp * 16;
    float4 f0 = *(const float4*)(xrow + kbase);
    float4 f1 = *(const float4*)(xrow + kbase + 4);
    float4 f2 = *(const float4*)(xrow + kbase + 8);
    float4 f3 = *(const float4*)(xrow + kbase + 12);
    float xv[16] = {f0.x, f0.y, f0.z, f0.w, f1.x, f1.y, f1.z, f1.w,
                    f2.x, f2.y, f2.z, f2.w, f3.x, f3.y, f3.z, f3.w};
    const uint32_t ibase = (uint32_t)asrow * IN_DIM + (uint32_t)kbase;
    u16 ob[16];
#pragma unroll
    for (int j = 0; j < 16; ++j) {
      uint32_t bits = tf_bits32(k0, k1, ibase + (uint32_t)j);
      ob[j] = f2bf((bits >> 31) ? 0.0f : xv[j] * asc);
    }
    uint4 pka, pkb;
    pka.x = (uint32_t)ob[0] | ((uint32_t)ob[1] << 16);
    pka.y = (uint32_t)ob[2] | ((uint32_t)ob[3] << 16);
    pka.z = (uint32_t)ob[4] | ((uint32_t)ob[5] << 16);
    pka.w = (uint32_t)ob[6] | ((uint32_t)ob[7] << 16);
    pkb.x = (uint32_t)ob[8] | ((uint32_t)ob[9] << 16);
    pkb.y = (uint32_t)ob[10] | ((uint32_t)ob[11] << 16);
    pkb.z = (uint32_t)ob[12] | ((uint32_t)ob[13] << 16);
    pkb.w = (uint32_t)ob[14] | ((uint32_t)ob[15] << 16);
    *(uint4*)(As + arow_l * 64 + aw0) = pka;
    *(uint4*)(As + arow_l * 64 + aw1) = pkb;
#pragma unroll
    for (int i = 0; i < 4; ++i) {
      int j = wid * 4 + i;
      int n = j * 8 + srow;
      int gch = ks * G1_BKC + (schunk ^ (n & 7));
      gload16(W1t + (size_t)n * IN_DIM + gch * 8, Bs + j * 512);
    }
    __syncthreads();
#pragma unroll
    for (int kk = 0; kk < 2; ++kk) {
      short8 a[4], b[4];
      const int kq = kk * 4 + q;
      const int c = kq ^ (m16 & 7);
#pragma unroll
      for (int rt = 0; rt < 4; ++rt) {
        int row = wr * 64 + rt * 16 + m16;
        a[rt] = *(const short8*)(As + row * 64 + c * 8);
      }
#pragma unroll
      for (int ct = 0; ct < 4; ++ct) {
        int n = wc * 64 + ct * 16 + m16;
        b[ct] = *(const short8*)(Bs + n * 64 + c * 8);
      }
#pragma unroll
      for (int rt = 0; rt < 4; ++rt)
#pragma unroll
        for (int ct = 0; ct < 4; ++ct)
          acc[rt][ct] = __builtin_amdgcn_mfma_f32_16x16x32_bf16(a[rt], b[ct], acc[rt][ct], 0, 0, 0);
    }
    __syncthreads();
  }
#pragma unroll
  for (int rt = 0; rt < 4; ++rt) {
#pragma unroll
    for (int r = 0; r < 4; ++r) {
      long grow = base_row + wr * 64 + rt * 16 + q * 4 + r;
      if (grow < N_NODES) {
#pragma unroll
        for (int ct = 0; ct < 4; ++ct)
          X1b[grow * HID + wc * 64 + ct * 16 + m16] = f2bf(acc[rt][ct][r]);
      }
    }
  }
}

// ---------------- CSR gather-sum (bf16) + relu -> h1 bf16  +  fused mask-gen ----------------
// Fabric-bound gather (VALU ~29% busy without masks): the tail generates the two
// hidden-dropout bit-masks in otherwise-idle VALU slots. 6.4M threads; first 3.2M
// produce mask-a bytes, last 3.2M produce mask-b bytes (8 threefry calls each).
__global__ __launch_bounds__(256) void agg_relu_k(
    const u16* __restrict__ X1b, const int* __restrict__ row_ofs,
    const int* __restrict__ csr, const float* __restrict__ in_is,
    uint32_t ka0, uint32_t ka1, uint32_t kb0, uint32_t kb1,
    u8* __restrict__ mska, u8* __restrict__ mskb,
    u16* __restrict__ h1b) {
  int d = blockIdx.x * 4 + (threadIdx.x >> 6);  // exact: 25000*4 = N
  int lane = threadIdx.x & 63;
  int half = lane >> 5;
  int col = (lane & 31) * 8;
  int beg = row_ofs[d], end = row_ofs[d + 1];
  float a[8];
#pragma unroll
  for (int i = 0; i < 8; ++i) a[i] = 0.0f;
  int j = beg + half;
  for (; j + 14 < end; j += 16) {
    int s0 = csr[j],      s1 = csr[j + 2],  s2 = csr[j + 4],  s3 = csr[j + 6];
    int s4 = csr[j + 8],  s5 = csr[j + 10], s6 = csr[j + 12], s7 = csr[j + 14];
    uint4 v0 = *(const uint4*)(X1b + (size_t)s0 * HID + col);
    uint4 v1 = *(const uint4*)(X1b + (size_t)s1 * HID + col);
    uint4 v2 = *(const uint4*)(X1b + (size_t)s2 * HID + col);
    uint4 v3 = *(const uint4*)(X1b + (size_t)s3 * HID + col);
    uint4 v4 = *(const uint4*)(X1b + (size_t)s4 * HID + col);
    uint4 v5 = *(const uint4*)(X1b + (size_t)s5 * HID + col);
    uint4 v6 = *(const uint4*)(X1b + (size_t)s6 * HID + col);
    uint4 v7 = *(const uint4*)(X1b + (size_t)s7 * HID + col);
    acc8(a, v0); acc8(a, v1); acc8(a, v2); acc8(a, v3);
    acc8(a, v4); acc8(a, v5); acc8(a, v6); acc8(a, v7);
  }
  for (; j + 6 < end; j += 8) {
    int s0 = csr[j], s1 = csr[j + 2], s2 = csr[j + 4], s3 = csr[j + 6];
    uint4 v0 = *(const uint4*)(X1b + (size_t)s0 * HID + col);
    uint4 v1 = *(const uint4*)(X1b + (size_t)s1 * HID + col);
    uint4 v2 = *(const uint4*)(X1b + (size_t)s2 * HID + col);
    uint4 v3 = *(const uint4*)(X1b + (size_t)s3 * HID + col);
    acc8(a, v0); acc8(a, v1); acc8(a, v2); acc8(a, v3);
  }
  for (; j < end; j += 2) {
    uint4 v0 = *(const uint4*)(X1b + (size_t)csr[j] * HID + col);
    acc8(a, v0);
  }
#pragma unroll
  for (int i = 0; i < 8; ++i) a[i] += __shfl(a[i], lane ^ 32, 64);
  if (half == 0) {
    float is = in_is[d];
    u16 o[8];
#pragma unroll
    for (int i = 0; i < 8; ++i) o[i] = f2bf(fmaxf(a[i] * is, 0.0f));
    uint4 pk;
    pk.x = (uint32_t)o[0] | ((uint32_t)o[1] << 16);
    pk.y = (uint32_t)o[2] | ((uint32_t)o[3] << 16);
    pk.z = (uint32_t)o[4] | ((uint32_t)o[5] << 16);
    pk.w = (uint32_t)o[6] | ((uint32_t)o[7] << 16);
    *(uint4*)(h1b + (size_t)d * HID + col) = pk;
  }
  // ---- fused hidden-dropout mask generation (fills idle VALU; bit set = keep) ----
  {
    const uint32_t NB = (uint32_t)N_NODES * HID / 8;   // 3.2M bytes per mask
    uint32_t gid = blockIdx.x * 256u + threadIdx.x;    // 6.4M threads total
    const bool isB = gid >= NB;
    const uint32_t mi = isB ? gid - NB : gid;          // mask byte index
    const uint32_t kk0 = isB ? kb0 : ka0, kk1 = isB ? kb1 : ka1;
    const uint32_t ib = mi * 8u;                       // element index base
    uint32_t bits = 0u;
#pragma unroll
    for (uint32_t jj = 0; jj < 8; ++jj)
      bits |= ((~tf_bits32(kk0, kk1, ib + jj)) >> 31) << jj;
    (isB ? mskb : mska)[mi] = (u8)bits;
  }
}

// ---------------- BatchNorm stats (bf16 in, fp32 accumulate), vectorized ----------------
__global__ __launch_bounds__(256) void bn_stats_k(const u16* __restrict__ h1b,
                                                  float* __restrict__ bn) {
  __shared__ float ls[512];
  const int tid = threadIdx.x;
  const int cb = (tid & 31) * 8;   // col base
  const int ms = tid >> 5;         // row-stream 0..7
  float s[8], s2[8];
#pragma unroll
  for (int i = 0; i < 8; ++i) { s[i] = 0.f; s2[i] = 0.f; }
  for (int m = ms;; m += 8) {
    int r = blockIdx.x + 256 * m;
    if (r >= N_NODES) break;
    uint4 v = *(const uint4*)(h1b + (size_t)r * HID + cb);
    float f[8];
    f[0] = bf2f((u16)(v.x & 0xffffu)); f[1] = bf2f((u16)(v.x >> 16));
    f[2] = bf2f((u16)(v.y & 0xffffu)); f[3] = bf2f((u16)(v.y >> 16));
    f[4] = bf2f((u16)(v.z & 0xffffu)); f[5] = bf2f((u16)(v.z >> 16));
    f[6] = bf2f((u16)(v.w & 0xffffu)); f[7] = bf2f((u16)(v.w >> 16));
#pragma unroll
    for (int i = 0; i < 8; ++i) { s[i] += f[i]; s2[i] += f[i] * f[i]; }
  }
  ls[tid] = 0.f; ls[tid + 256] = 0.f;
  __syncthreads();
#pragma unroll
  for (int i = 0; i < 8; ++i) {
    atomicAdd(&ls[cb + i], s[i]);
    atomicAdd(&ls[256 + cb + i], s2[i]);
  }
  __syncthreads();
  atomicAdd(&bn[tid], ls[tid]);
  atomicAdd(&bn[HID + tid], ls[256 + tid]);
}

// ---------------- GEMM2/3 (MFMA): reads bit-packed masks + bn finalize ----------------
#define WLS 264   // u16 row stride for Wls: dword-stride 132 -> 2-way bank alias (free)
__global__ __launch_bounds__(256) void gemm23_k(
    const u16* __restrict__ h1b, const u16* __restrict__ Wt23,
    const u8* __restrict__ mska, const u8* __restrict__ mskb,
    const float* __restrict__ out_is, const float* __restrict__ bn,
    u16* __restrict__ XMLV) {
  __shared__ u16 Wls[32 * WLS];
  __shared__ float cB[HID], cA[HID];
  const int tid = threadIdx.x;
#pragma unroll
  for (int i = 0; i < 4; ++i) {   // stage Wt23 (16KB) into padded LDS
    int idx = tid + i * 256;      // 1024 uint4 chunks
    int n = idx >> 5, c = idx & 31;
    *(uint4*)(Wls + n * WLS + c * 8) = ((const uint4*)Wt23)[idx];
  }
  {  // bn finalize: cB = istd, cA = -mean*istd
    float mean = bn[tid] * (1.0f / (float)N_NODES);
    float var = bn[HID + tid] * (1.0f / (float)N_NODES) - mean * mean;
    float istd = rsqrtf(var + 1e-5f);
    cB[tid] = istd;
    cA[tid] = -mean * istd;
  }
  __syncthreads();

  const int wv = tid >> 6, lane = tid & 63;
  const int m = lane & 15, q = lane >> 4;
  const long arow = (long)blockIdx.x * 64 + wv * 16 + m;   // A row this lane loads
  const bool valid = arow < N_NODES;
  const float osc = valid ? 2.0f * out_is[arow] : 0.0f;

  float4v accM = (float4v)0.0f, accL = (float4v)0.0f;
  for (int kc = 0; kc < HID; kc += 32) {
    const int kof = kc + q * 8;
    uint4 hv = make_uint4(0, 0, 0, 0);
    uint32_t wa = 0, wb = 0;
    if (valid) {
      hv = *(const uint4*)(h1b + arow * HID + kof);
      uint32_t bofs = ((uint32_t)arow * HID + (uint32_t)kc) >> 3;  // byte ofs, 4-aligned
      wa = (*(const uint32_t*)(mska + bofs)) >> (q * 8);
      wb = (*(const uint32_t*)(mskb + bofs)) >> (q * 8);
    }
    float4 B0 = *(const float4*)(cB + kof);
    float4 B1 = *(const float4*)(cB + kof + 4);
    float4 A0 = *(const float4*)(cA + kof);
    float4 A1 = *(const float4*)(cA + kof + 4);
    float hval[8] = {
      bf2f((u16)(hv.x & 0xffffu)), bf2f((u16)(hv.x >> 16)),
      bf2f((u16)(hv.y & 0xffffu)), bf2f((u16)(hv.y >> 16)),
      bf2f((u16)(hv.z & 0xffffu)), bf2f((u16)(hv.z >> 16)),
      bf2f((u16)(hv.w & 0xffffu)), bf2f((u16)(hv.w >> 16))};
    float nb[8] = {B0.x, B0.y, B0.z, B0.w, B1.x, B1.y, B1.z, B1.w};
    float na[8] = {A0.x, A0.y, A0.z, A0.w, A1.x, A1.y, A1.z, A1.w};
    short8 Aa, Ab;
#pragma unroll
    for (int jj = 0; jj < 8; ++jj) {
      float t = fmaf(hval[jj], nb[jj], na[jj]) * osc;
      u16 tb = f2bf(t);
      Aa[jj] = (short)(((wa >> jj) & 1u) ? tb : 0);
      Ab[jj] = (short)(((wb >> jj) & 1u) ? tb : 0);
    }
    short8 Bm = *(const short8*)(Wls + m * WLS + kof);          // W2 col m
    short8 Bl = *(const short8*)(Wls + (16 + m) * WLS + kof);   // W3 col m
    accM = __builtin_amdgcn_mfma_f32_16x16x32_bf16(Aa, Bm, accM, 0, 0, 0);
    accL = __builtin_amdgcn_mfma_f32_16x16x32_bf16(Ab, Bl, accL, 0, 0, 0);
  }
#pragma unroll
  for (int r = 0; r < 4; ++r) {
    long srow = (long)blockIdx.x * 64 + wv * 16 + q * 4 + r;
    if (srow < N_NODES) {
      XMLV[srow * 32 + m]      = f2bf(accM[r]);
      XMLV[srow * 32 + 16 + m] = f2bf(accL[r]);
    }
  }
}

// ---------------- final: aggregate interleaved mu|logvar + reparameterize ----------------
__global__ __launch_bounds__(256) void agg_final_k(
    const u16* __restrict__ XMLV, const int* __restrict__ row_ofs,
    const int* __restrict__ csr, const float* __restrict__ in_is,
    uint32_t ke0, uint32_t ke1, float* __restrict__ out) {
  int g = blockIdx.x * 4 + (threadIdx.x >> 6);  // exact: 25000*4 = N
  int lane = threadIdx.x & 63;
  int half = lane >> 5, c = lane & 31;
  int beg = row_ofs[g], end = row_ofs[g + 1];
  float s = 0.f;
  int j = beg + half;
  for (; j + 14 < end; j += 16) {
    int s0 = csr[j],      s1 = csr[j + 2],  s2 = csr[j + 4],  s3 = csr[j + 6];
    int s4 = csr[j + 8],  s5 = csr[j + 10], s6 = csr[j + 12], s7 = csr[j + 14];
    float v0 = bf2f(XMLV[(size_t)s0 * 32 + c]);
    float v1 = bf2f(XMLV[(size_t)s1 * 32 + c]);
    float v2 = bf2f(XMLV[(size_t)s2 * 32 + c]);
    float v3 = bf2f(XMLV[(size_t)s3 * 32 + c]);
    float v4 = bf2f(XMLV[(size_t)s4 * 32 + c]);
    float v5 = bf2f(XMLV[(size_t)s5 * 32 + c]);
    float v6 = bf2f(XMLV[(size_t)s6 * 32 + c]);
    float v7 = bf2f(XMLV[(size_t)s7 * 32 + c]);
    s += v0; s += v1; s += v2; s += v3;
    s += v4; s += v5; s += v6; s += v7;
  }
#pragma unroll
  for (int k = 0; k < 8; ++k) {
    int e = j + 2 * k;
    if (e < end) s += bf2f(XMLV[(size_t)csr[e] * 32 + c]);
  }
  s += __shfl(s, lane ^ 32, 64);
  if (half == 0) {
    s *= in_is[g];
    float other = __shfl(s, lane ^ 16, 64);  // mu lane c gets logvar from lane c+16
    if (c < 16) {
      uint32_t i = (uint32_t)(g * NCLS + c);
      uint32_t bits = tf_bits32(ke0, ke1, i);
      float f = __uint_as_float((bits >> 9) | 0x3f800000u) - 1.0f;
      const float lo = -0.99999994f;          // nextafter(-1,0)
      float u = fmaxf(lo, fmaf(f, 2.0f, lo)); // (hi-lo) rounds to exactly 2.0f
      float eps = 1.41421356f * erfinv_f32(u);
      out[i] = eps * expf(other) + s;
    }
  }
}

// ---------------- host ----------------
extern "C" void kernel_launch(void* const* d_in, const int* in_sizes, int n_in,
                              void* d_out, int out_size, void* d_ws, size_t ws_size,
                              hipStream_t stream) {
  (void)in_sizes; (void)n_in; (void)out_size; (void)ws_size;
  const float* x  = (const float*)d_in[0];
  const float* W1 = (const float*)d_in[1];
  const float* W2 = (const float*)d_in[2];
  const float* W3 = (const float*)d_in[3];
  const int* esrc = (const int*)d_in[4];
  const int* edst = (const int*)d_in[5];
  float* out = (float*)d_out;

  uint32_t kb[8];
  for (int j = 0; j < 4; ++j)
    threefry2x32(0u, 42u, 0u, (uint32_t)j, kb[2 * j], kb[2 * j + 1]);
  // k1=(kb0,kb1) drop-x; k2a=(kb2,kb3); k2b=(kb4,kb5); keps=(kb6,kb7)

  char* p = (char*)d_ws;
  auto take = [&](size_t bytes) -> void* {
    void* r = (void*)p;
    p += (bytes + 255) & ~(size_t)255;
    return r;
  };
  u8* P8         = (u8*)take((size_t)DBLK * N_NODES);                    // 25.6 MB
  uint32_t* ebuf = (uint32_t*)take(sizeof(uint32_t) * (size_t)N_EDGES);  // 12.8 MB
  u16* X1b       = (u16*)take(sizeof(u16) * (size_t)N_NODES * HID);
  u16* h1b       = (u16*)take(sizeof(u16) * (size_t)N_NODES * HID);
  u16* XMLV      = (u16*)take(sizeof(u16) * (size_t)N_NODES * 32);
  u16* W1t       = (u16*)take(sizeof(u16) * (size_t)IN_DIM * HID);
  u16* Wt23      = (u16*)take(sizeof(u16) * 32 * HID);
  u8* mska       = (u8*)take((size_t)N_NODES * HID / 8);                 // 3.2 MB
  u8* mskb       = (u8*)take((size_t)N_NODES * HID / 8);
  uint32_t* bofs_g = (uint32_t*)take(sizeof(uint32_t) * (size_t)DBLK * (NBKT + 1));
  int* tile_sum  = (int*)take(sizeof(int) * NTILE);
  float* out_is  = (float*)take(sizeof(float) * N_NODES);
  float* in_is   = (float*)take(sizeof(float) * N_NODES);
  int* row_ofs   = (int*)take(sizeof(int) * (N_NODES + 1));
  int* csr       = (int*)take(sizeof(int) * N_EDGES);
  float* bn      = (float*)take(sizeof(float) * 1024);

  hipMemsetAsync(bn, 0, sizeof(float) * 512, stream);

  hist_part_k<<<DBLK, 1024, 0, stream>>>(esrc, edst, P8, bofs_g, ebuf);
  degsum_k<<<NTILE, 256, 0, stream>>>(P8, out_is, in_is, row_ofs, tile_sum);
  fixup_k<<<NTILE, 256, 0, stream>>>(tile_sum, row_ofs);
  bplace_k<<<NBKT, 1024, 0, stream>>>(ebuf, bofs_g, row_ofs, csr);

  cast_w_k<<<(IN_DIM * HID + 32 * HID) / 256, 256, 0, stream>>>(W1, W2, W3, W1t, Wt23);

  gemm1_k<<<(N_NODES + G1_BM - 1) / G1_BM, 512, 0, stream>>>(x, out_is, kb[0], kb[1], W1t, X1b);
  agg_relu_k<<<N_NODES / 4, 256, 0, stream>>>(X1b, row_ofs, csr, in_is,
                                              kb[2], kb[3], kb[4], kb[5], mska, mskb, h1b);
  bn_stats_k<<<256, 256, 0, stream>>>(h1b, bn);
  gemm23_k<<<(N_NODES + 63) / 64, 256, 0, stream>>>(h1b, Wt23, mska, mskb, out_is, bn, XMLV);
  agg_final_k<<<N_NODES / 4, 256, 0, stream>>>(XMLV, row_ofs, csr, in_is, kb[6], kb[7], out);
}